// Round 4
// baseline (4395.364 us; speedup 1.0000x reference)
//
#include <hip/hip_runtime.h>
#include <math.h>

// Problem constants (setup_inputs deterministic):
//   D=512, FF=1024, B=512 molecules, max nodes/mol=128, max rings/mol=8,
//   max nodes/ring=8, mol seq len = 1+128+1+8+1 = 139.
// Harness: fp32 buffers (values bf16-quantized), int32 index arrays.
//
// R4: mol_attn restructured from block-per-(qtile,head,mol) to
// block-per-(head,mol) with K/V staged to LDS ONCE (157 KB LDS, 1 block/CU).
// R3's profile showed 695 MB HBM fetch per dispatch = 9x redundant K/V
// re-reads (one per q-tile) at 1.4 TB/s = ~500 of the 555 us. Per-q-tile
// compute order is unchanged -> bit-identical mol outputs.
// Ring path stays fp32 (argmax amplifier, R1); mol GEMMs stay split-A MFMA.
#define D_ 512
#define LSEQ 139
#define LRING 8
#define LDK 40   // LDS row stride in bf16 elems (80 B: 16B-aligned, conflict-free)

typedef __bf16 bf16x8 __attribute__((ext_vector_type(8)));
typedef float f32x4 __attribute__((ext_vector_type(4)));

__device__ __forceinline__ void f2split(float f, unsigned short& h, unsigned short& l) {
    unsigned int u = __float_as_uint(f);
    h = (unsigned short)(u >> 16);                       // truncated bf16 (exact if f is bf16)
    float r = f - __uint_as_float(u & 0xFFFF0000u);      // exact residual
    l = (unsigned short)(__float_as_uint(r) >> 16);      // truncated bf16 of residual
}

// ---------------------------------------------------------------- prefix sums
__global__ void scan_kernel(const int* __restrict__ rnn, int R,
                            const int* __restrict__ mrn, int Bm,
                            int* __restrict__ rs, int* __restrict__ ms) {
    __shared__ int lds[256];
    int tid = threadIdx.x;
    int chunk = (R + 255) / 256;
    int sum = 0;
    for (int i = 0; i < chunk; ++i) {
        int idx = tid * chunk + i;
        if (idx < R) sum += rnn[idx];
    }
    lds[tid] = sum;
    __syncthreads();
    if (tid == 0) {
        int run = 0;
        for (int t = 0; t < 256; ++t) { int tmp = lds[t]; lds[t] = run; run += tmp; }
    }
    __syncthreads();
    int off = lds[tid];
    for (int i = 0; i < chunk; ++i) {
        int idx = tid * chunk + i;
        if (idx < R) { rs[idx] = off; off += rnn[idx]; }
    }
    __syncthreads();
    chunk = (Bm + 255) / 256;
    sum = 0;
    for (int i = 0; i < chunk; ++i) {
        int idx = tid * chunk + i;
        if (idx < Bm) sum += mrn[idx];
    }
    __syncthreads();
    lds[tid] = sum;
    __syncthreads();
    if (tid == 0) {
        int run = 0;
        for (int t = 0; t < 256; ++t) { int tmp = lds[t]; lds[t] = run; run += tmp; }
    }
    __syncthreads();
    off = lds[tid];
    for (int i = 0; i < chunk; ++i) {
        int idx = tid * chunk + i;
        if (idx < Bm) { ms[idx] = off; off += mrn[idx]; }
    }
}

// ---------------------------------------------------------------- fp32 -> bf16 weight convert (RNE; identity on bf16-exact values)
__global__ void convert_w(const float* __restrict__ src, unsigned short* __restrict__ dst, int n4) {
    int t = blockIdx.x * blockDim.x + threadIdx.x;
    if (t >= n4) return;
    const float4 v = *(const float4*)(src + (size_t)t * 4);
    unsigned int u0 = __float_as_uint(v.x), u1 = __float_as_uint(v.y),
                 u2 = __float_as_uint(v.z), u3 = __float_as_uint(v.w);
    u0 = (u0 + 0x7FFFu + ((u0 >> 16) & 1)) >> 16;
    u1 = (u1 + 0x7FFFu + ((u1 >> 16) & 1)) >> 16;
    u2 = (u2 + 0x7FFFu + ((u2 >> 16) & 1)) >> 16;
    u3 = (u3 + 0x7FFFu + ((u3 >> 16) & 1)) >> 16;
    *(uint2*)(dst + (size_t)t * 4) = make_uint2(u0 | (u1 << 16), u2 | (u3 << 16));
}

// ---------------------------------------------------------------- gather ring inputs (padded), fp32 (ring path)
__global__ void build_xr(const float* __restrict__ x, const int* __restrict__ rni,
                         const int* __restrict__ rnn, const int* __restrict__ rs,
                         float* __restrict__ out, int rBase, int RC) {
    int t = blockIdx.x * blockDim.x + threadIdx.x;
    int total = RC * LRING * (D_ / 4);
    if (t >= total) return;
    int c4 = (t & 127) * 4;
    int row = t >> 7;                 // local row
    int rl = row >> 3, l = row & 7;
    int r = rBase + rl;
    float4 v = make_float4(0.f, 0.f, 0.f, 0.f);
    if (l < rnn[r]) {
        int node = rni[rs[r] + l];
        v = *(const float4*)(x + (size_t)node * D_ + c4);
    }
    *(float4*)(out + (size_t)row * D_ + c4) = v;
}

// ---------------------------------------------------------------- fp32 GEMM-NT (ring path), 128x128 tile, 8x8 register block.
// Per-output k-accumulation strictly sequential -> bit-identical results.
// C[M,N] = A[M,K] * Bw[N,K]^T + bias (+Res) (+relu).  Res/C may alias.
template <bool RELU, bool RES>
__global__ __launch_bounds__(256) void gemm_nt(const float* __restrict__ A,
                                               const float* __restrict__ Bw,
                                               const float* __restrict__ bias,
                                               const float* Res, float* C,
                                               int M, int N, int K) {
    __shared__ __align__(16) float As[16][132];
    __shared__ __align__(16) float Bs[16][132];
    const int bm = blockIdx.y * 128, bn = blockIdx.x * 128;
    const int tid = threadIdx.x;
    const int ty = tid >> 4, tx = tid & 15;   // 16x16 threads, 8x8 outputs each
    const int sr = tid >> 1;                  // staging row 0..127
    const int sc = (tid & 1) * 8;             // staging k sub-col 0 or 8
    float acc[8][8];
#pragma unroll
    for (int i = 0; i < 8; ++i)
#pragma unroll
        for (int j = 0; j < 8; ++j) acc[i][j] = 0.f;
    const float4 z4 = make_float4(0.f, 0.f, 0.f, 0.f);
    const int arow = bm + sr;
    const bool aok = arow < M;
    for (int k0 = 0; k0 < K; k0 += 16) {
        float4 av0 = z4, av1 = z4;
        if (aok) {
            av0 = *(const float4*)(A + (size_t)arow * K + k0 + sc);
            av1 = *(const float4*)(A + (size_t)arow * K + k0 + sc + 4);
        }
        const float4 bv0 = *(const float4*)(Bw + (size_t)(bn + sr) * K + k0 + sc); // N%128==0 always
        const float4 bv1 = *(const float4*)(Bw + (size_t)(bn + sr) * K + k0 + sc + 4);
        __syncthreads();
        As[sc + 0][sr] = av0.x; As[sc + 1][sr] = av0.y; As[sc + 2][sr] = av0.z; As[sc + 3][sr] = av0.w;
        As[sc + 4][sr] = av1.x; As[sc + 5][sr] = av1.y; As[sc + 6][sr] = av1.z; As[sc + 7][sr] = av1.w;
        Bs[sc + 0][sr] = bv0.x; Bs[sc + 1][sr] = bv0.y; Bs[sc + 2][sr] = bv0.z; Bs[sc + 3][sr] = bv0.w;
        Bs[sc + 4][sr] = bv1.x; Bs[sc + 5][sr] = bv1.y; Bs[sc + 6][sr] = bv1.z; Bs[sc + 7][sr] = bv1.w;
        __syncthreads();
#pragma unroll
        for (int k = 0; k < 16; ++k) {
            float a[8], b[8];
            *(float4*)&a[0] = *(const float4*)&As[k][ty * 8];
            *(float4*)&a[4] = *(const float4*)&As[k][ty * 8 + 4];
            *(float4*)&b[0] = *(const float4*)&Bs[k][tx * 8];
            *(float4*)&b[4] = *(const float4*)&Bs[k][tx * 8 + 4];
#pragma unroll
            for (int i = 0; i < 8; ++i)
#pragma unroll
                for (int j = 0; j < 8; ++j) acc[i][j] += a[i] * b[j];
        }
    }
    const int n = bn + tx * 8;
    float bvv[8];
    *(float4*)&bvv[0] = *(const float4*)(bias + n);
    *(float4*)&bvv[4] = *(const float4*)(bias + n + 4);
#pragma unroll
    for (int i = 0; i < 8; ++i) {
        int m = bm + ty * 8 + i;
        if (m >= M) continue;
        float r[8];
#pragma unroll
        for (int j = 0; j < 8; ++j) r[j] = acc[i][j] + bvv[j];
        if (RES) {
            float rv[8];
            *(float4*)&rv[0] = *(const float4*)(Res + (size_t)m * N + n);
            *(float4*)&rv[4] = *(const float4*)(Res + (size_t)m * N + n + 4);
#pragma unroll
            for (int j = 0; j < 8; ++j) r[j] += rv[j];
        }
        if (RELU) {
#pragma unroll
            for (int j = 0; j < 8; ++j) r[j] = fmaxf(r[j], 0.f);
        }
        *(float4*)(C + (size_t)m * N + n) = make_float4(r[0], r[1], r[2], r[3]);
        *(float4*)(C + (size_t)m * N + n + 4) = make_float4(r[4], r[5], r[6], r[7]);
    }
}

// ---------------------------------------------------------------- split-A bf16 MFMA GEMM-NT (mol path):
// C[M,N] = (Ah+Al)[M,K] * Bw[N,K]^T + bias (+Res fp32) (+relu).
// OSPLIT: write output as split bf16 (Oh/Ol) instead of fp32 C.
// 128x128 tile, 4 waves (2x2), mfma_f32_16x16x32_bf16, 2 MFMA per fragment.
template <bool RELU, bool RES, bool OSPLIT>
__global__ __launch_bounds__(256, 2) void gemm_bf16(
        const unsigned short* __restrict__ Ah, const unsigned short* __restrict__ Al,
        const unsigned short* __restrict__ Bw, const float* __restrict__ bias,
        const float* __restrict__ Res, float* __restrict__ C,
        unsigned short* __restrict__ Oh, unsigned short* __restrict__ Ol,
        int M, int N, int K) {
    __shared__ __align__(16) unsigned short sAh[128][LDK];
    __shared__ __align__(16) unsigned short sAl[128][LDK];
    __shared__ __align__(16) unsigned short sB[128][LDK];
    const int bm = blockIdx.y * 128, bn = blockIdx.x * 128;
    const int tid = threadIdx.x;
    const int lane = tid & 63, wid = tid >> 6;
    const int wr = wid >> 1, wc = wid & 1;        // wave grid 2x2, wave tile 64x64
    const int fr = lane & 15, fq = lane >> 4;     // fragment row/col + k-quad
    const int sr = tid >> 2;                      // staging row 0..63 (and +64)
    const int sc = (tid & 3) * 8;                 // staging k sub-col 0,8,16,24 (8 bf16 = 16B)
    f32x4 acc[4][4];
#pragma unroll
    for (int m = 0; m < 4; ++m)
#pragma unroll
        for (int n = 0; n < 4; ++n) {
            acc[m][n][0] = 0.f; acc[m][n][1] = 0.f;
            acc[m][n][2] = 0.f; acc[m][n][3] = 0.f;
        }
    const int r0 = bm + sr, r1 = r0 + 64;
    const bool ok0 = r0 < M, ok1 = r1 < M;
    for (int k0 = 0; k0 < K; k0 += 32) {
        uint4 a0 = make_uint4(0, 0, 0, 0), a1 = a0, al0 = a0, al1 = a0;
        if (ok0) {
            a0  = *(const uint4*)(Ah + (size_t)r0 * K + k0 + sc);
            al0 = *(const uint4*)(Al + (size_t)r0 * K + k0 + sc);
        }
        if (ok1) {
            a1  = *(const uint4*)(Ah + (size_t)r1 * K + k0 + sc);
            al1 = *(const uint4*)(Al + (size_t)r1 * K + k0 + sc);
        }
        const uint4 b0 = *(const uint4*)(Bw + (size_t)(bn + sr) * K + k0 + sc);
        const uint4 b1 = *(const uint4*)(Bw + (size_t)(bn + sr + 64) * K + k0 + sc);
        __syncthreads();
        *(uint4*)&sAh[sr][sc] = a0;  *(uint4*)&sAh[sr + 64][sc] = a1;
        *(uint4*)&sAl[sr][sc] = al0; *(uint4*)&sAl[sr + 64][sc] = al1;
        *(uint4*)&sB[sr][sc]  = b0;  *(uint4*)&sB[sr + 64][sc]  = b1;
        __syncthreads();
        bf16x8 bfr[4];
#pragma unroll
        for (int n = 0; n < 4; ++n)
            bfr[n] = *(const bf16x8*)&sB[wc * 64 + n * 16 + fr][fq * 8];
#pragma unroll
        for (int m = 0; m < 4; ++m) {
            bf16x8 ah = *(const bf16x8*)&sAh[wr * 64 + m * 16 + fr][fq * 8];
            bf16x8 al = *(const bf16x8*)&sAl[wr * 64 + m * 16 + fr][fq * 8];
#pragma unroll
            for (int n = 0; n < 4; ++n)
                acc[m][n] = __builtin_amdgcn_mfma_f32_16x16x32_bf16(ah, bfr[n], acc[m][n], 0, 0, 0);
#pragma unroll
            for (int n = 0; n < 4; ++n)
                acc[m][n] = __builtin_amdgcn_mfma_f32_16x16x32_bf16(al, bfr[n], acc[m][n], 0, 0, 0);
        }
    }
    // epilogue: C/D layout col = lane&15, row = (lane>>4)*4 + reg  [m89-verified]
    float bv[4];
#pragma unroll
    for (int n = 0; n < 4; ++n) bv[n] = bias[bn + wc * 64 + n * 16 + fr];
#pragma unroll
    for (int m = 0; m < 4; ++m) {
#pragma unroll
        for (int i = 0; i < 4; ++i) {
            int row = bm + wr * 64 + m * 16 + fq * 4 + i;
            if (row >= M) continue;
#pragma unroll
            for (int n = 0; n < 4; ++n) {
                int col = bn + wc * 64 + n * 16 + fr;
                float v = acc[m][n][i] + bv[n];
                if (RES) v += Res[(size_t)row * N + col];
                if (RELU) v = fmaxf(v, 0.f);
                if (OSPLIT) {
                    unsigned short h, l;
                    f2split(v, h, l);
                    Oh[(size_t)row * N + col] = h;
                    Ol[(size_t)row * N + col] = l;
                } else {
                    C[(size_t)row * N + col] = v;
                }
            }
        }
    }
}

// ---------------------------------------------------------------- ring attention: block per (head, local ring). L=8, dh=256, h=2.
__global__ __launch_bounds__(256) void ring_attn(const float* __restrict__ qkv,
                                                 const int* __restrict__ rnn,
                                                 float* __restrict__ ctx, int rBase) {
    __shared__ float qs[8][260], ks[8][260], vs[8][260];
    __shared__ float sS[8][8];
    __shared__ float pS[8][8];
    const int hh = blockIdx.x;
    const int rl = blockIdx.y;
    const int tid = threadIdx.x;
    const int rn = rnn[rBase + rl];
    const float* base = qkv + (size_t)rl * 8 * 1536;
    for (int i = tid; i < 8 * 256; i += 256) {
        int l = i >> 8, c = i & 255;
        const float* p = base + (size_t)l * 1536 + hh * 256 + c;
        qs[l][c] = p[0];
        ks[l][c] = p[512];
        vs[l][c] = p[1024];
    }
    __syncthreads();
    if (tid < 64) {
        int i = tid >> 3, j = tid & 7;
        float s = -30000.f;
        if (j < rn) {
            float d = 0.f;
            for (int c = 0; c < 256; ++c) d += qs[i][c] * ks[j][c];
            s = d * 0.0625f; // 1/sqrt(256)
        }
        sS[i][j] = s;
    }
    __syncthreads();
    if (tid < 8) {
        int i = tid;
        float mx = -30000.f;
#pragma unroll
        for (int j = 0; j < 8; ++j) mx = fmaxf(mx, sS[i][j]);
        float p[8], sum = 0.f;
#pragma unroll
        for (int j = 0; j < 8; ++j) { p[j] = __expf(sS[i][j] - mx); sum += p[j]; }
        float inv = 1.f / sum;
#pragma unroll
        for (int j = 0; j < 8; ++j) pS[i][j] = p[j] * inv;
    }
    __syncthreads();
    {
        int d = tid;
#pragma unroll
        for (int i = 0; i < 8; ++i) {
            float a = 0.f;
#pragma unroll
            for (int j = 0; j < 8; ++j) a += pS[i][j] * vs[j][d];
            ctx[(size_t)(rl * 8 + i) * 512 + hh * 256 + d] = a;
        }
    }
}

// ---------------------------------------------------------------- argmax(|Xe|) over 8 positions -> rings_vec
__global__ void argmax_pick(const float* __restrict__ Xe, float* __restrict__ rv, int RC) {
    int t = blockIdx.x * blockDim.x + threadIdx.x;
    if (t >= RC * 512) return;
    int r = t >> 9, d = t & 511;
    const float* p = Xe + (size_t)r * 8 * 512 + d;
    float best = fabsf(p[0]);
    int pos = 0;
#pragma unroll
    for (int l = 1; l < 8; ++l) {
        float v = fabsf(p[(size_t)l * 512]);
        if (v > best) { best = v; pos = l; } // strict > == first-occurrence tie-break
    }
    rv[t] = p[(size_t)pos * 512];
}

// ---------------------------------------------------------------- build mol sequence [CLS, nodes.., RING, rings.., END], fp32 + split
__global__ void build_seq(const float* __restrict__ x, const float* __restrict__ rv,
                          const float* __restrict__ CLS, const float* __restrict__ RING,
                          const float* __restrict__ END, const int* __restrict__ ptr,
                          const int* __restrict__ mrn, const int* __restrict__ ms,
                          float* __restrict__ seq, unsigned short* __restrict__ oh,
                          unsigned short* __restrict__ ol, int bBase, int CB) {
    int t = blockIdx.x * blockDim.x + threadIdx.x;
    int total = CB * LSEQ * 128;
    if (t >= total) return;
    int c4 = (t & 127) * 4;
    int row = t >> 7;
    int bl = row / LSEQ, p = row - bl * LSEQ;
    int b = bBase + bl;
    const float* src = nullptr;
    if (p == 0) src = CLS;
    else if (p <= 128) {
        int i = p - 1;
        int nn = ptr[b + 1] - ptr[b];
        if (i < nn) src = x + (size_t)(ptr[b] + i) * 512;
    } else if (p == 129) src = RING;
    else if (p <= 137) {
        int i = p - 130;
        if (i < mrn[b]) src = rv + (size_t)(ms[b] + i) * 512;
    } else src = END;
    float4 v = src ? *(const float4*)(src + c4) : make_float4(0.f, 0.f, 0.f, 0.f);
    *(float4*)(seq + (size_t)row * 512 + c4) = v;
    unsigned short h0, h1, h2, h3, l0, l1, l2, l3;
    f2split(v.x, h0, l0); f2split(v.y, h1, l1);
    f2split(v.z, h2, l2); f2split(v.w, h3, l3);
    *(uint2*)(oh + (size_t)row * 512 + c4) = make_uint2(h0 | (h1 << 16), h2 | (h3 << 16));
    *(uint2*)(ol + (size_t)row * 512 + c4) = make_uint2(l0 | (l1 << 16), l2 | (l3 << 16));
}

// ---------------------------------------------------------------- mol attention (flash-style). L=139, dh=128, h=4.
// R4: block per (head, mol); K/V staged to LDS ONCE, q-tiles looped inside.
// Per-q-tile compute order identical to R3 -> bit-identical outputs.
__device__ __forceinline__ bool key_valid_mol(int j, int nn, int nr) {
    if (j == 0 || j == 129 || j == 138) return true;
    if (j <= 128) return (j - 1) < nn;
    if (j <= 137) return (j - 130) < nr;
    return false;
}

__global__ __launch_bounds__(256) void mol_attn(const float* __restrict__ qkv,
                                                const int* __restrict__ ptr,
                                                const int* __restrict__ mrn,
                                                unsigned short* __restrict__ ctxh,
                                                unsigned short* __restrict__ ctxl,
                                                int bBase) {
    __shared__ __align__(16) float qs[16][132];
    __shared__ __align__(16) float ks[LSEQ][132];
    __shared__ __align__(16) float vs[LSEQ][132];
    __shared__ float st[16][33];
    const int hh = blockIdx.x, bl = blockIdx.y;
    const int b = bBase + bl;
    const int tid = threadIdx.x;
    const int qi = tid >> 4, dj = tid & 15;
    const int nn = ptr[b + 1] - ptr[b];
    const int nr = mrn[b];
    const float* base = qkv + (size_t)bl * LSEQ * 1536;
    // ---- stage K and V once (coalesced: 32 threads cover one 128-float row)
    for (int i = tid; i < LSEQ * 32; i += 256) {
        int row = i >> 5, cq = (i & 31) * 4;
        const float* pk = base + (size_t)row * 1536 + 512 + hh * 128 + cq;
        float4 kk = *(const float4*)pk;
        float4 vv = *(const float4*)(pk + 512);
        *(float4*)&ks[row][cq] = kk;
        *(float4*)&vs[row][cq] = vv;
    }
    __syncthreads();
    for (int qt = 0; qt < (LSEQ + 15) / 16; ++qt) {
        const int q0 = qt * 16;
        __syncthreads();   // protect qs/st from previous tile's readers
        {
            int qrow = q0 + qi;
            float4 v0 = make_float4(0.f, 0.f, 0.f, 0.f), v1 = v0;
            if (qrow < LSEQ) {
                const float* p = base + (size_t)qrow * 1536 + hh * 128 + dj * 8;
                v0 = *(const float4*)p;
                v1 = *(const float4*)(p + 4);
            }
            *(float4*)&qs[qi][dj * 8] = v0;
            *(float4*)&qs[qi][dj * 8 + 4] = v1;
        }
        __syncthreads();
        float m_i = -30000.f, l_i = 0.f;
        float acc[8] = {0.f, 0.f, 0.f, 0.f, 0.f, 0.f, 0.f, 0.f};
        for (int j0 = 0; j0 < LSEQ; j0 += 32) {
#pragma unroll
            for (int t2 = 0; t2 < 2; ++t2) {
                int jj = dj + t2 * 16;
                int j = j0 + jj;
                float s = -30000.f;
                if (j < LSEQ && key_valid_mol(j, nn, nr)) {
                    float d = 0.f;
#pragma unroll
                    for (int c = 0; c < 128; c += 4) {
                        float4 a = *(const float4*)&qs[qi][c];
                        float4 kk = *(const float4*)&ks[j][c];
                        d += a.x * kk.x + a.y * kk.y + a.z * kk.z + a.w * kk.w;
                    }
                    s = d * 0.08838834764831845f; // 1/sqrt(128)
                }
                st[qi][jj] = s;
            }
            __syncthreads();
            float cmax = -30000.f;
#pragma unroll
            for (int j = 0; j < 32; ++j) cmax = fmaxf(cmax, st[qi][j]);
            float m_new = fmaxf(m_i, cmax);
            float alpha = __expf(m_i - m_new);
            l_i *= alpha;
#pragma unroll
            for (int d = 0; d < 8; ++d) acc[d] *= alpha;
            for (int j = 0; j < 32; ++j) {
                float pj = __expf(st[qi][j] - m_new);
                l_i += pj;
                int jg = j0 + j;
                int jv = (jg < LSEQ) ? jg : (LSEQ - 1); // pj==+0 beyond LSEQ -> 0*finite=+0
                float4 v0 = *(const float4*)&vs[jv][dj * 8];
                float4 v1 = *(const float4*)&vs[jv][dj * 8 + 4];
                acc[0] += pj * v0.x; acc[1] += pj * v0.y; acc[2] += pj * v0.z; acc[3] += pj * v0.w;
                acc[4] += pj * v1.x; acc[5] += pj * v1.y; acc[6] += pj * v1.z; acc[7] += pj * v1.w;
            }
            m_i = m_new;
            __syncthreads();   // protect st before next block's writes
        }
        int qrow = q0 + qi;
        if (qrow < LSEQ) {
            float inv = 1.f / l_i;
            size_t o = (size_t)(bl * LSEQ + qrow) * 512 + hh * 128 + dj * 8;
            unsigned int hw[4], lw[4];
#pragma unroll
            for (int i2 = 0; i2 < 4; ++i2) {
                unsigned short ha, hb, la, lb;
                f2split(acc[2 * i2] * inv, ha, la);
                f2split(acc[2 * i2 + 1] * inv, hb, lb);
                hw[i2] = (unsigned int)ha | ((unsigned int)hb << 16);
                lw[i2] = (unsigned int)la | ((unsigned int)lb << 16);
            }
            *(uint4*)(ctxh + o) = make_uint4(hw[0], hw[1], hw[2], hw[3]);
            *(uint4*)(ctxl + o) = make_uint4(lw[0], lw[1], lw[2], lw[3]);
        }
    }
}

// ---------------------------------------------------------------- LayerNorm (in-place fp32; optional split-bf16 out)
__global__ __launch_bounds__(64) void ln_kernel(float* X, const float* __restrict__ gam,
                                                const float* __restrict__ bet,
                                                unsigned short* __restrict__ oh,
                                                unsigned short* __restrict__ ol) {
    const size_t row = blockIdx.x;
    const int tid = threadIdx.x;
    float* p = X + row * 512 + tid * 8;
    float4 v0 = *(float4*)p, v1 = *(float4*)(p + 4);
    float s = v0.x + v0.y + v0.z + v0.w + v1.x + v1.y + v1.z + v1.w;
#pragma unroll
    for (int off = 32; off; off >>= 1) s += __shfl_xor(s, off, 64);
    float mu = s * (1.f / 512.f);
    float d[8] = {v0.x - mu, v0.y - mu, v0.z - mu, v0.w - mu,
                  v1.x - mu, v1.y - mu, v1.z - mu, v1.w - mu};
    float s2 = 0.f;
#pragma unroll
    for (int i = 0; i < 8; ++i) s2 += d[i] * d[i];
#pragma unroll
    for (int off = 32; off; off >>= 1) s2 += __shfl_xor(s2, off, 64);
    float inv = 1.f / sqrtf(s2 * (1.f / 512.f) + 1e-5f);
    const float* gp = gam + tid * 8;
    const float* bp = bet + tid * 8;
    float4 g0 = *(const float4*)gp, g1 = *(const float4*)(gp + 4);
    float4 b0 = *(const float4*)bp, b1 = *(const float4*)(bp + 4);
    float y[8];
    y[0] = d[0] * inv * g0.x + b0.x; y[1] = d[1] * inv * g0.y + b0.y;
    y[2] = d[2] * inv * g0.z + b0.z; y[3] = d[3] * inv * g0.w + b0.w;
    y[4] = d[4] * inv * g1.x + b1.x; y[5] = d[5] * inv * g1.y + b1.y;
    y[6] = d[6] * inv * g1.z + b1.z; y[7] = d[7] * inv * g1.w + b1.w;
    *(float4*)p = make_float4(y[0], y[1], y[2], y[3]);
    *(float4*)(p + 4) = make_float4(y[4], y[5], y[6], y[7]);
    if (oh) {
        unsigned int hw[4], lw[4];
#pragma unroll
        for (int i2 = 0; i2 < 4; ++i2) {
            unsigned short ha, hb, la, lb;
            f2split(y[2 * i2], ha, la);
            f2split(y[2 * i2 + 1], hb, lb);
            hw[i2] = (unsigned int)ha | ((unsigned int)hb << 16);
            lw[i2] = (unsigned int)la | ((unsigned int)lb << 16);
        }
        size_t o = row * 512 + tid * 8;
        *(uint4*)(oh + o) = make_uint4(hw[0], hw[1], hw[2], hw[3]);
        *(uint4*)(ol + o) = make_uint4(lw[0], lw[1], lw[2], lw[3]);
    }
}

// ---------------------------------------------------------------- scatter outputs
__global__ void scatter_out(const float* __restrict__ seq, const int* __restrict__ ptr,
                            const int* __restrict__ mrn, const int* __restrict__ ms,
                            float* __restrict__ out_mol, float* __restrict__ out_node,
                            float* __restrict__ out_ring, int bBase, int CB) {
    int t = blockIdx.x * blockDim.x + threadIdx.x;
    int total = CB * LSEQ * 128;
    if (t >= total) return;
    int c4 = (t & 127) * 4;
    int row = t >> 7;
    int bl = row / LSEQ, p = row - bl * LSEQ;
    int b = bBase + bl;
    float4 v = *(const float4*)(seq + (size_t)row * 512 + c4);
    if (p == 0) {
        *(float4*)(out_mol + (size_t)b * 512 + c4) = v;
    } else if (p <= 128) {
        int i = p - 1;
        int nn = ptr[b + 1] - ptr[b];
        if (i < nn) *(float4*)(out_node + (size_t)(ptr[b] + i) * 512 + c4) = v;
    } else if (p >= 130 && p <= 137) {
        int i = p - 130;
        if (i < mrn[b]) *(float4*)(out_ring + (size_t)(ms[b] + i) * 512 + c4) = v;
    }
}

// ================================================================ host
extern "C" void kernel_launch(void* const* d_in, const int* in_sizes, int n_in,
                              void* d_out, int out_size, void* d_ws, size_t ws_size,
                              hipStream_t stream) {
    const float* x      = (const float*)d_in[0];
    const int*   ptr    = (const int*)d_in[1];
    const int*   rni    = (const int*)d_in[2];
    const int*   rnn    = (const int*)d_in[3];
    const int*   mrn    = (const int*)d_in[4];
    const float* CLS    = (const float*)d_in[5];
    const float* RINGt  = (const float*)d_in[6];
    const float* ENDt   = (const float*)d_in[7];
    const float* r_wqkv = (const float*)d_in[8];
    const float* r_bqkv = (const float*)d_in[9];
    const float* r_wo   = (const float*)d_in[10];
    const float* r_bo   = (const float*)d_in[11];
    const float* r_ln1g = (const float*)d_in[12];
    const float* r_ln1b = (const float*)d_in[13];
    const float* r_w1   = (const float*)d_in[14];
    const float* r_b1   = (const float*)d_in[15];
    const float* r_w2   = (const float*)d_in[16];
    const float* r_b2   = (const float*)d_in[17];
    const float* r_ln2g = (const float*)d_in[18];
    const float* r_ln2b = (const float*)d_in[19];
    const float* m_wqkv = (const float*)d_in[20];
    const float* m_bqkv = (const float*)d_in[21];
    const float* m_wo   = (const float*)d_in[22];
    const float* m_bo   = (const float*)d_in[23];
    const float* m_ln1g = (const float*)d_in[24];
    const float* m_ln1b = (const float*)d_in[25];
    const float* m_w1   = (const float*)d_in[26];
    const float* m_b1   = (const float*)d_in[27];
    const float* m_w2   = (const float*)d_in[28];
    const float* m_b2   = (const float*)d_in[29];
    const float* m_ln2g = (const float*)d_in[30];
    const float* m_ln2b = (const float*)d_in[31];

    const int N  = in_sizes[0] / D_;
    const int R  = in_sizes[3];
    const int Bm = in_sizes[4];

    // ------- workspace layout: [rings_vec][rs][ms][bf16 mol weights][bufA][bufQ][P0h][P0l]
    char* w = (char*)d_ws;
    size_t off = 0;
    float* rings_vec = (float*)(w + off); off += (size_t)R * 512 * 4;
    int* rs = (int*)(w + off); off += (size_t)R * 4;
    int* ms = (int*)(w + off); off += (size_t)Bm * 4;
    off = (off + 255) & ~(size_t)255;
    unsigned short* b_m_wqkv = (unsigned short*)(w + off);
    unsigned short* b_m_wo   = b_m_wqkv + 1536 * 512;
    unsigned short* b_m_w1   = b_m_wo   + 512 * 512;
    unsigned short* b_m_w2   = b_m_w1   + 1024 * 512;
    off += (size_t)(1536 * 512 + 512 * 512 + 1024 * 512 + 512 * 1024) * 2;
    off = (off + 255) & ~(size_t)255;

    size_t avail = (ws_size > off) ? (ws_size - off) : 0;
    const size_t perMolA = (size_t)LSEQ * 512 * 4;    // 284,672 fp32 residual/stream
    const size_t perMolQ = (size_t)LSEQ * 1536 * 4;   // 854,016 qkv (also hosts mol P1 split)
    const size_t perMolP = (size_t)LSEQ * 512 * 2;    // 142,336 each of P0h / P0l
    const size_t perMol  = perMolA + perMolQ + 2 * perMolP;  // 1,423,360
    int molChunk = (int)(avail / perMol);
    if (molChunk > Bm) molChunk = Bm;
    if (molChunk < 1) return; // workspace unusably small
    int ringChunk = molChunk * 17;   // ring rows are 8 vs 139 -> 17:1 fits all buffers
    if (ringChunk > R) ringChunk = R;
    float* bufA = (float*)(w + off); off += (size_t)molChunk * perMolA;
    float* bufQ = (float*)(w + off); off += (size_t)molChunk * perMolQ;
    unsigned short* P0h = (unsigned short*)(w + off);
    unsigned short* P0l = P0h + (size_t)molChunk * LSEQ * 512;
    // Ring-path fp32 ctx buffer reuses the P0 region: ringChunk*8*512*4 B
    //  = molChunk*278,528 <= 2*perMolP*molChunk = molChunk*284,672.
    float* bufC = (float*)P0h;
    // Mol P1 (w1 split output, N=1024) aliases bufQ (qkv dead after attention):
    // 2 * molChunk*139*1024*2 B = molChunk*569,344 <= molChunk*854,016.
    unsigned short* P1h = (unsigned short*)bufQ;
    unsigned short* P1l = P1h + (size_t)molChunk * LSEQ * 1024;

    float* out_mol  = (float*)d_out;
    float* out_node = out_mol + (size_t)Bm * 512;
    float* out_ring = out_node + (size_t)N * 512;

    scan_kernel<<<1, 256, 0, stream>>>(rnn, R, mrn, Bm, rs, ms);

    // ---------------- mol weight conversion (RNE; once per launch) ----------------
    convert_w<<<(1536 * 512 / 4 + 255) / 256, 256, 0, stream>>>(m_wqkv, b_m_wqkv, 1536 * 512 / 4);
    convert_w<<<(512 * 512 / 4 + 255) / 256, 256, 0, stream>>>(m_wo, b_m_wo, 512 * 512 / 4);
    convert_w<<<(1024 * 512 / 4 + 255) / 256, 256, 0, stream>>>(m_w1, b_m_w1, 1024 * 512 / 4);
    convert_w<<<(512 * 1024 / 4 + 255) / 256, 256, 0, stream>>>(m_w2, b_m_w2, 512 * 1024 / 4);

    // ---------------- ring encoder (chunked, fp32 path — bit-identical results) ----------------
    for (int r0 = 0; r0 < R; r0 += ringChunk) {
        int RC = (R - r0 < ringChunk) ? (R - r0) : ringChunk;
        int TrC = RC * LRING;
        build_xr<<<(TrC * 128 + 255) / 256, 256, 0, stream>>>(x, rni, rnn, rs, bufA, r0, RC);
        gemm_nt<false, false><<<dim3(1536 / 128, (TrC + 127) / 128), 256, 0, stream>>>(
            bufA, r_wqkv, r_bqkv, nullptr, bufQ, TrC, 1536, 512);
        ring_attn<<<dim3(2, RC), 256, 0, stream>>>(bufQ, rnn, bufC, r0);
        gemm_nt<false, true><<<dim3(512 / 128, (TrC + 127) / 128), 256, 0, stream>>>(
            bufC, r_wo, r_bo, bufA, bufA, TrC, 512, 512);
        ln_kernel<<<TrC, 64, 0, stream>>>(bufA, r_ln1g, r_ln1b, nullptr, nullptr);
        gemm_nt<true, false><<<dim3(1024 / 128, (TrC + 127) / 128), 256, 0, stream>>>(
            bufA, r_w1, r_b1, nullptr, bufQ, TrC, 1024, 512);
        gemm_nt<false, true><<<dim3(512 / 128, (TrC + 127) / 128), 256, 0, stream>>>(
            bufQ, r_w2, r_b2, bufA, bufA, TrC, 512, 1024);
        ln_kernel<<<TrC, 64, 0, stream>>>(bufA, r_ln2g, r_ln2b, nullptr, nullptr);
        argmax_pick<<<(RC * 512 + 255) / 256, 256, 0, stream>>>(bufA, rings_vec + (size_t)r0 * 512, RC);
    }

    // ---------------- molecule encoder (chunked, MFMA split-A path) ----------------
    for (int c0 = 0; c0 < Bm; c0 += molChunk) {
        int CB = (Bm - c0 < molChunk) ? (Bm - c0) : molChunk;
        int TmC = CB * LSEQ;
        build_seq<<<(TmC * 128 + 255) / 256, 256, 0, stream>>>(
            x, rings_vec, CLS, RINGt, ENDt, ptr, mrn, ms, bufA, P0h, P0l, c0, CB);
        gemm_bf16<false, false, false><<<dim3(1536 / 128, (TmC + 127) / 128), 256, 0, stream>>>(
            P0h, P0l, b_m_wqkv, m_bqkv, nullptr, bufQ, nullptr, nullptr, TmC, 1536, 512);
        mol_attn<<<dim3(4, CB), 256, 0, stream>>>(bufQ, ptr, mrn, P0h, P0l, c0);
        gemm_bf16<false, true, false><<<dim3(512 / 128, (TmC + 127) / 128), 256, 0, stream>>>(
            P0h, P0l, b_m_wo, m_bo, bufA, bufA, nullptr, nullptr, TmC, 512, 512);
        ln_kernel<<<TmC, 64, 0, stream>>>(bufA, m_ln1g, m_ln1b, P0h, P0l);
        gemm_bf16<true, false, true><<<dim3(1024 / 128, (TmC + 127) / 128), 256, 0, stream>>>(
            P0h, P0l, b_m_w1, m_b1, nullptr, nullptr, P1h, P1l, TmC, 1024, 512);
        gemm_bf16<false, true, false><<<dim3(512 / 128, (TmC + 127) / 128), 256, 0, stream>>>(
            P1h, P1l, b_m_w2, m_b2, bufA, bufA, nullptr, nullptr, TmC, 512, 1024);
        ln_kernel<<<TmC, 64, 0, stream>>>(bufA, m_ln2g, m_ln2b, nullptr, nullptr);
        scatter_out<<<(TmC * 128 + 255) / 256, 256, 0, stream>>>(
            bufA, ptr, mrn, ms, out_mol, out_node, out_ring, c0, CB);
    }
}

// Round 5
// 3544.793 us; speedup vs baseline: 1.2399x; 1.2399x over previous
//
#include <hip/hip_runtime.h>
#include <math.h>

// Problem constants (setup_inputs deterministic):
//   D=512, FF=1024, B=512 molecules, max nodes/mol=128, max rings/mol=8,
//   max nodes/ring=8, mol seq len = 1+128+1+8+1 = 139.
// Harness: fp32 buffers (values bf16-quantized), int32 index arrays.
//
// R5: R4's giant-LDS mol_attn regressed (1 wave/SIMD, latency-bound).
// Revert to R3's mol_attn body (3 blocks/CU, bit-identical compute) and fix
// the REAL problem: the 9 q-tile blocks sharing one (mol,head) K/V slice were
// dispatch-consecutive -> scattered over 8 per-XCD L2s -> 695 MB HBM refetch.
// New grid (Gpad multiple of 8, qt slowest) puts all 9 on the SAME XCD so
// re-reads hit that XCD's 4MB L2. Per-thread compute order unchanged
// everywhere -> outputs bit-identical to R3/R4 (absmax 0.03125).
#define D_ 512
#define LSEQ 139
#define LRING 8
#define LDK 40   // LDS row stride in bf16 elems (80 B: 16B-aligned, conflict-free)

typedef __bf16 bf16x8 __attribute__((ext_vector_type(8)));
typedef float f32x4 __attribute__((ext_vector_type(4)));

__device__ __forceinline__ void f2split(float f, unsigned short& h, unsigned short& l) {
    unsigned int u = __float_as_uint(f);
    h = (unsigned short)(u >> 16);                       // truncated bf16 (exact if f is bf16)
    float r = f - __uint_as_float(u & 0xFFFF0000u);      // exact residual
    l = (unsigned short)(__float_as_uint(r) >> 16);      // truncated bf16 of residual
}

// ---------------------------------------------------------------- prefix sums
__global__ void scan_kernel(const int* __restrict__ rnn, int R,
                            const int* __restrict__ mrn, int Bm,
                            int* __restrict__ rs, int* __restrict__ ms) {
    __shared__ int lds[256];
    int tid = threadIdx.x;
    int chunk = (R + 255) / 256;
    int sum = 0;
    for (int i = 0; i < chunk; ++i) {
        int idx = tid * chunk + i;
        if (idx < R) sum += rnn[idx];
    }
    lds[tid] = sum;
    __syncthreads();
    if (tid == 0) {
        int run = 0;
        for (int t = 0; t < 256; ++t) { int tmp = lds[t]; lds[t] = run; run += tmp; }
    }
    __syncthreads();
    int off = lds[tid];
    for (int i = 0; i < chunk; ++i) {
        int idx = tid * chunk + i;
        if (idx < R) { rs[idx] = off; off += rnn[idx]; }
    }
    __syncthreads();
    chunk = (Bm + 255) / 256;
    sum = 0;
    for (int i = 0; i < chunk; ++i) {
        int idx = tid * chunk + i;
        if (idx < Bm) sum += mrn[idx];
    }
    __syncthreads();
    lds[tid] = sum;
    __syncthreads();
    if (tid == 0) {
        int run = 0;
        for (int t = 0; t < 256; ++t) { int tmp = lds[t]; lds[t] = run; run += tmp; }
    }
    __syncthreads();
    off = lds[tid];
    for (int i = 0; i < chunk; ++i) {
        int idx = tid * chunk + i;
        if (idx < Bm) { ms[idx] = off; off += mrn[idx]; }
    }
}

// ---------------------------------------------------------------- fp32 -> bf16 weight convert (RNE; identity on bf16-exact values)
__global__ void convert_w(const float* __restrict__ src, unsigned short* __restrict__ dst, int n4) {
    int t = blockIdx.x * blockDim.x + threadIdx.x;
    if (t >= n4) return;
    const float4 v = *(const float4*)(src + (size_t)t * 4);
    unsigned int u0 = __float_as_uint(v.x), u1 = __float_as_uint(v.y),
                 u2 = __float_as_uint(v.z), u3 = __float_as_uint(v.w);
    u0 = (u0 + 0x7FFFu + ((u0 >> 16) & 1)) >> 16;
    u1 = (u1 + 0x7FFFu + ((u1 >> 16) & 1)) >> 16;
    u2 = (u2 + 0x7FFFu + ((u2 >> 16) & 1)) >> 16;
    u3 = (u3 + 0x7FFFu + ((u3 >> 16) & 1)) >> 16;
    *(uint2*)(dst + (size_t)t * 4) = make_uint2(u0 | (u1 << 16), u2 | (u3 << 16));
}

// ---------------------------------------------------------------- gather ring inputs (padded), fp32 (ring path)
__global__ void build_xr(const float* __restrict__ x, const int* __restrict__ rni,
                         const int* __restrict__ rnn, const int* __restrict__ rs,
                         float* __restrict__ out, int rBase, int RC) {
    int t = blockIdx.x * blockDim.x + threadIdx.x;
    int total = RC * LRING * (D_ / 4);
    if (t >= total) return;
    int c4 = (t & 127) * 4;
    int row = t >> 7;                 // local row
    int rl = row >> 3, l = row & 7;
    int r = rBase + rl;
    float4 v = make_float4(0.f, 0.f, 0.f, 0.f);
    if (l < rnn[r]) {
        int node = rni[rs[r] + l];
        v = *(const float4*)(x + (size_t)node * D_ + c4);
    }
    *(float4*)(out + (size_t)row * D_ + c4) = v;
}

// ---------------------------------------------------------------- fp32 GEMM-NT (ring path), 128x128 tile, 8x8 register block.
// Per-output k-accumulation strictly sequential -> bit-identical results.
// C[M,N] = A[M,K] * Bw[N,K]^T + bias (+Res) (+relu).  Res/C may alias.
template <bool RELU, bool RES>
__global__ __launch_bounds__(256) void gemm_nt(const float* __restrict__ A,
                                               const float* __restrict__ Bw,
                                               const float* __restrict__ bias,
                                               const float* Res, float* C,
                                               int M, int N, int K) {
    __shared__ __align__(16) float As[16][132];
    __shared__ __align__(16) float Bs[16][132];
    const int bm = blockIdx.y * 128, bn = blockIdx.x * 128;
    const int tid = threadIdx.x;
    const int ty = tid >> 4, tx = tid & 15;   // 16x16 threads, 8x8 outputs each
    const int sr = tid >> 1;                  // staging row 0..127
    const int sc = (tid & 1) * 8;             // staging k sub-col 0 or 8
    float acc[8][8];
#pragma unroll
    for (int i = 0; i < 8; ++i)
#pragma unroll
        for (int j = 0; j < 8; ++j) acc[i][j] = 0.f;
    const float4 z4 = make_float4(0.f, 0.f, 0.f, 0.f);
    const int arow = bm + sr;
    const bool aok = arow < M;
    for (int k0 = 0; k0 < K; k0 += 16) {
        float4 av0 = z4, av1 = z4;
        if (aok) {
            av0 = *(const float4*)(A + (size_t)arow * K + k0 + sc);
            av1 = *(const float4*)(A + (size_t)arow * K + k0 + sc + 4);
        }
        const float4 bv0 = *(const float4*)(Bw + (size_t)(bn + sr) * K + k0 + sc); // N%128==0 always
        const float4 bv1 = *(const float4*)(Bw + (size_t)(bn + sr) * K + k0 + sc + 4);
        __syncthreads();
        As[sc + 0][sr] = av0.x; As[sc + 1][sr] = av0.y; As[sc + 2][sr] = av0.z; As[sc + 3][sr] = av0.w;
        As[sc + 4][sr] = av1.x; As[sc + 5][sr] = av1.y; As[sc + 6][sr] = av1.z; As[sc + 7][sr] = av1.w;
        Bs[sc + 0][sr] = bv0.x; Bs[sc + 1][sr] = bv0.y; Bs[sc + 2][sr] = bv0.z; Bs[sc + 3][sr] = bv0.w;
        Bs[sc + 4][sr] = bv1.x; Bs[sc + 5][sr] = bv1.y; Bs[sc + 6][sr] = bv1.z; Bs[sc + 7][sr] = bv1.w;
        __syncthreads();
#pragma unroll
        for (int k = 0; k < 16; ++k) {
            float a[8], b[8];
            *(float4*)&a[0] = *(const float4*)&As[k][ty * 8];
            *(float4*)&a[4] = *(const float4*)&As[k][ty * 8 + 4];
            *(float4*)&b[0] = *(const float4*)&Bs[k][tx * 8];
            *(float4*)&b[4] = *(const float4*)&Bs[k][tx * 8 + 4];
#pragma unroll
            for (int i = 0; i < 8; ++i)
#pragma unroll
                for (int j = 0; j < 8; ++j) acc[i][j] += a[i] * b[j];
        }
    }
    const int n = bn + tx * 8;
    float bvv[8];
    *(float4*)&bvv[0] = *(const float4*)(bias + n);
    *(float4*)&bvv[4] = *(const float4*)(bias + n + 4);
#pragma unroll
    for (int i = 0; i < 8; ++i) {
        int m = bm + ty * 8 + i;
        if (m >= M) continue;
        float r[8];
#pragma unroll
        for (int j = 0; j < 8; ++j) r[j] = acc[i][j] + bvv[j];
        if (RES) {
            float rv[8];
            *(float4*)&rv[0] = *(const float4*)(Res + (size_t)m * N + n);
            *(float4*)&rv[4] = *(const float4*)(Res + (size_t)m * N + n + 4);
#pragma unroll
            for (int j = 0; j < 8; ++j) r[j] += rv[j];
        }
        if (RELU) {
#pragma unroll
            for (int j = 0; j < 8; ++j) r[j] = fmaxf(r[j], 0.f);
        }
        *(float4*)(C + (size_t)m * N + n) = make_float4(r[0], r[1], r[2], r[3]);
        *(float4*)(C + (size_t)m * N + n + 4) = make_float4(r[4], r[5], r[6], r[7]);
    }
}

// ---------------------------------------------------------------- split-A bf16 MFMA GEMM-NT (mol path):
// C[M,N] = (Ah+Al)[M,K] * Bw[N,K]^T + bias (+Res fp32) (+relu).
// OSPLIT: write output as split bf16 (Oh/Ol) instead of fp32 C.
// 128x128 tile, 4 waves (2x2), mfma_f32_16x16x32_bf16, 2 MFMA per fragment.
template <bool RELU, bool RES, bool OSPLIT>
__global__ __launch_bounds__(256, 2) void gemm_bf16(
        const unsigned short* __restrict__ Ah, const unsigned short* __restrict__ Al,
        const unsigned short* __restrict__ Bw, const float* __restrict__ bias,
        const float* __restrict__ Res, float* __restrict__ C,
        unsigned short* __restrict__ Oh, unsigned short* __restrict__ Ol,
        int M, int N, int K) {
    __shared__ __align__(16) unsigned short sAh[128][LDK];
    __shared__ __align__(16) unsigned short sAl[128][LDK];
    __shared__ __align__(16) unsigned short sB[128][LDK];
    const int bm = blockIdx.y * 128, bn = blockIdx.x * 128;
    const int tid = threadIdx.x;
    const int lane = tid & 63, wid = tid >> 6;
    const int wr = wid >> 1, wc = wid & 1;        // wave grid 2x2, wave tile 64x64
    const int fr = lane & 15, fq = lane >> 4;     // fragment row/col + k-quad
    const int sr = tid >> 2;                      // staging row 0..63 (and +64)
    const int sc = (tid & 3) * 8;                 // staging k sub-col 0,8,16,24 (8 bf16 = 16B)
    f32x4 acc[4][4];
#pragma unroll
    for (int m = 0; m < 4; ++m)
#pragma unroll
        for (int n = 0; n < 4; ++n) {
            acc[m][n][0] = 0.f; acc[m][n][1] = 0.f;
            acc[m][n][2] = 0.f; acc[m][n][3] = 0.f;
        }
    const int r0 = bm + sr, r1 = r0 + 64;
    const bool ok0 = r0 < M, ok1 = r1 < M;
    for (int k0 = 0; k0 < K; k0 += 32) {
        uint4 a0 = make_uint4(0, 0, 0, 0), a1 = a0, al0 = a0, al1 = a0;
        if (ok0) {
            a0  = *(const uint4*)(Ah + (size_t)r0 * K + k0 + sc);
            al0 = *(const uint4*)(Al + (size_t)r0 * K + k0 + sc);
        }
        if (ok1) {
            a1  = *(const uint4*)(Ah + (size_t)r1 * K + k0 + sc);
            al1 = *(const uint4*)(Al + (size_t)r1 * K + k0 + sc);
        }
        const uint4 b0 = *(const uint4*)(Bw + (size_t)(bn + sr) * K + k0 + sc);
        const uint4 b1 = *(const uint4*)(Bw + (size_t)(bn + sr + 64) * K + k0 + sc);
        __syncthreads();
        *(uint4*)&sAh[sr][sc] = a0;  *(uint4*)&sAh[sr + 64][sc] = a1;
        *(uint4*)&sAl[sr][sc] = al0; *(uint4*)&sAl[sr + 64][sc] = al1;
        *(uint4*)&sB[sr][sc]  = b0;  *(uint4*)&sB[sr + 64][sc]  = b1;
        __syncthreads();
        bf16x8 bfr[4];
#pragma unroll
        for (int n = 0; n < 4; ++n)
            bfr[n] = *(const bf16x8*)&sB[wc * 64 + n * 16 + fr][fq * 8];
#pragma unroll
        for (int m = 0; m < 4; ++m) {
            bf16x8 ah = *(const bf16x8*)&sAh[wr * 64 + m * 16 + fr][fq * 8];
            bf16x8 al = *(const bf16x8*)&sAl[wr * 64 + m * 16 + fr][fq * 8];
#pragma unroll
            for (int n = 0; n < 4; ++n)
                acc[m][n] = __builtin_amdgcn_mfma_f32_16x16x32_bf16(ah, bfr[n], acc[m][n], 0, 0, 0);
#pragma unroll
            for (int n = 0; n < 4; ++n)
                acc[m][n] = __builtin_amdgcn_mfma_f32_16x16x32_bf16(al, bfr[n], acc[m][n], 0, 0, 0);
        }
    }
    // epilogue: C/D layout col = lane&15, row = (lane>>4)*4 + reg  [m89-verified]
    float bv[4];
#pragma unroll
    for (int n = 0; n < 4; ++n) bv[n] = bias[bn + wc * 64 + n * 16 + fr];
#pragma unroll
    for (int m = 0; m < 4; ++m) {
#pragma unroll
        for (int i = 0; i < 4; ++i) {
            int row = bm + wr * 64 + m * 16 + fq * 4 + i;
            if (row >= M) continue;
#pragma unroll
            for (int n = 0; n < 4; ++n) {
                int col = bn + wc * 64 + n * 16 + fr;
                float v = acc[m][n][i] + bv[n];
                if (RES) v += Res[(size_t)row * N + col];
                if (RELU) v = fmaxf(v, 0.f);
                if (OSPLIT) {
                    unsigned short h, l;
                    f2split(v, h, l);
                    Oh[(size_t)row * N + col] = h;
                    Ol[(size_t)row * N + col] = l;
                } else {
                    C[(size_t)row * N + col] = v;
                }
            }
        }
    }
}

// ---------------------------------------------------------------- ring attention: block per (head, local ring). L=8, dh=256, h=2.
__global__ __launch_bounds__(256) void ring_attn(const float* __restrict__ qkv,
                                                 const int* __restrict__ rnn,
                                                 float* __restrict__ ctx, int rBase) {
    __shared__ float qs[8][260], ks[8][260], vs[8][260];
    __shared__ float sS[8][8];
    __shared__ float pS[8][8];
    const int hh = blockIdx.x;
    const int rl = blockIdx.y;
    const int tid = threadIdx.x;
    const int rn = rnn[rBase + rl];
    const float* base = qkv + (size_t)rl * 8 * 1536;
    for (int i = tid; i < 8 * 256; i += 256) {
        int l = i >> 8, c = i & 255;
        const float* p = base + (size_t)l * 1536 + hh * 256 + c;
        qs[l][c] = p[0];
        ks[l][c] = p[512];
        vs[l][c] = p[1024];
    }
    __syncthreads();
    if (tid < 64) {
        int i = tid >> 3, j = tid & 7;
        float s = -30000.f;
        if (j < rn) {
            float d = 0.f;
            for (int c = 0; c < 256; ++c) d += qs[i][c] * ks[j][c];
            s = d * 0.0625f; // 1/sqrt(256)
        }
        sS[i][j] = s;
    }
    __syncthreads();
    if (tid < 8) {
        int i = tid;
        float mx = -30000.f;
#pragma unroll
        for (int j = 0; j < 8; ++j) mx = fmaxf(mx, sS[i][j]);
        float p[8], sum = 0.f;
#pragma unroll
        for (int j = 0; j < 8; ++j) { p[j] = __expf(sS[i][j] - mx); sum += p[j]; }
        float inv = 1.f / sum;
#pragma unroll
        for (int j = 0; j < 8; ++j) pS[i][j] = p[j] * inv;
    }
    __syncthreads();
    {
        int d = tid;
#pragma unroll
        for (int i = 0; i < 8; ++i) {
            float a = 0.f;
#pragma unroll
            for (int j = 0; j < 8; ++j) a += pS[i][j] * vs[j][d];
            ctx[(size_t)(rl * 8 + i) * 512 + hh * 256 + d] = a;
        }
    }
}

// ---------------------------------------------------------------- argmax(|Xe|) over 8 positions -> rings_vec
__global__ void argmax_pick(const float* __restrict__ Xe, float* __restrict__ rv, int RC) {
    int t = blockIdx.x * blockDim.x + threadIdx.x;
    if (t >= RC * 512) return;
    int r = t >> 9, d = t & 511;
    const float* p = Xe + (size_t)r * 8 * 512 + d;
    float best = fabsf(p[0]);
    int pos = 0;
#pragma unroll
    for (int l = 1; l < 8; ++l) {
        float v = fabsf(p[(size_t)l * 512]);
        if (v > best) { best = v; pos = l; } // strict > == first-occurrence tie-break
    }
    rv[t] = p[(size_t)pos * 512];
}

// ---------------------------------------------------------------- build mol sequence [CLS, nodes.., RING, rings.., END], fp32 + split
__global__ void build_seq(const float* __restrict__ x, const float* __restrict__ rv,
                          const float* __restrict__ CLS, const float* __restrict__ RING,
                          const float* __restrict__ END, const int* __restrict__ ptr,
                          const int* __restrict__ mrn, const int* __restrict__ ms,
                          float* __restrict__ seq, unsigned short* __restrict__ oh,
                          unsigned short* __restrict__ ol, int bBase, int CB) {
    int t = blockIdx.x * blockDim.x + threadIdx.x;
    int total = CB * LSEQ * 128;
    if (t >= total) return;
    int c4 = (t & 127) * 4;
    int row = t >> 7;
    int bl = row / LSEQ, p = row - bl * LSEQ;
    int b = bBase + bl;
    const float* src = nullptr;
    if (p == 0) src = CLS;
    else if (p <= 128) {
        int i = p - 1;
        int nn = ptr[b + 1] - ptr[b];
        if (i < nn) src = x + (size_t)(ptr[b] + i) * 512;
    } else if (p == 129) src = RING;
    else if (p <= 137) {
        int i = p - 130;
        if (i < mrn[b]) src = rv + (size_t)(ms[b] + i) * 512;
    } else src = END;
    float4 v = src ? *(const float4*)(src + c4) : make_float4(0.f, 0.f, 0.f, 0.f);
    *(float4*)(seq + (size_t)row * 512 + c4) = v;
    unsigned short h0, h1, h2, h3, l0, l1, l2, l3;
    f2split(v.x, h0, l0); f2split(v.y, h1, l1);
    f2split(v.z, h2, l2); f2split(v.w, h3, l3);
    *(uint2*)(oh + (size_t)row * 512 + c4) = make_uint2(h0 | (h1 << 16), h2 | (h3 << 16));
    *(uint2*)(ol + (size_t)row * 512 + c4) = make_uint2(l0 | (l1 << 16), l2 | (l3 << 16));
}

// ---------------------------------------------------------------- mol attention (flash-style). L=139, dh=128, h=4. Split ctx out.
// R5: R3 body, XCD-aware grid: blockIdx.x = group (mol*4+head, padded to 8),
// blockIdx.y = q-tile. gridDim.x % 8 == 0 => all 9 q-tiles of a group land on
// the same XCD, so K/V re-reads hit that XCD's L2 instead of HBM.
__device__ __forceinline__ bool key_valid_mol(int j, int nn, int nr) {
    if (j == 0 || j == 129 || j == 138) return true;
    if (j <= 128) return (j - 1) < nn;
    if (j <= 137) return (j - 130) < nr;
    return false;
}

__global__ __launch_bounds__(256) void mol_attn(const float* __restrict__ qkv,
                                                const int* __restrict__ ptr,
                                                const int* __restrict__ mrn,
                                                unsigned short* __restrict__ ctxh,
                                                unsigned short* __restrict__ ctxl,
                                                int bBase, int CB) {
    __shared__ __align__(16) float qs[16][132];
    __shared__ __align__(16) float ks[32][132];
    __shared__ __align__(16) float vs[32][132];
    __shared__ float st[16][33];
    const int g = blockIdx.x;
    if (g >= CB * 4) return;
    const int bl = g >> 2, hh = g & 3;
    const int qt = blockIdx.y;
    const int b = bBase + bl;
    const int tid = threadIdx.x;
    const int qi = tid >> 4, dj = tid & 15;
    const int nn = ptr[b + 1] - ptr[b];
    const int nr = mrn[b];
    const int q0 = qt * 16;
    const float* base = qkv + (size_t)bl * LSEQ * 1536;
    {
        int qrow = q0 + qi;
        float4 v0 = make_float4(0.f, 0.f, 0.f, 0.f), v1 = v0;
        if (qrow < LSEQ) {
            const float* p = base + (size_t)qrow * 1536 + hh * 128 + dj * 8;
            v0 = *(const float4*)p;
            v1 = *(const float4*)(p + 4);
        }
        *(float4*)&qs[qi][dj * 8] = v0;
        *(float4*)&qs[qi][dj * 8 + 4] = v1;
    }
    float m_i = -30000.f, l_i = 0.f;
    float acc[8] = {0.f, 0.f, 0.f, 0.f, 0.f, 0.f, 0.f, 0.f};
    for (int j0 = 0; j0 < LSEQ; j0 += 32) {
        __syncthreads();
        {
            int jl = tid >> 3;
            int jr = j0 + jl;
            int c = (tid & 7) * 16;
            float4 kk[4], vv[4];
            if (jr < LSEQ) {
                const float* pk = base + (size_t)jr * 1536 + 512 + hh * 128 + c;
#pragma unroll
                for (int q = 0; q < 4; ++q) {
                    kk[q] = *(const float4*)(pk + q * 4);
                    vv[q] = *(const float4*)(pk + 512 + q * 4);
                }
            } else {
#pragma unroll
                for (int q = 0; q < 4; ++q) { kk[q] = make_float4(0.f, 0.f, 0.f, 0.f); vv[q] = kk[q]; }
            }
#pragma unroll
            for (int q = 0; q < 4; ++q) {
                *(float4*)&ks[jl][c + q * 4] = kk[q];
                *(float4*)&vs[jl][c + q * 4] = vv[q];
            }
        }
        __syncthreads();
#pragma unroll
        for (int t2 = 0; t2 < 2; ++t2) {
            int jj = dj + t2 * 16;
            int j = j0 + jj;
            float s = -30000.f;
            if (j < LSEQ && key_valid_mol(j, nn, nr)) {
                float d = 0.f;
#pragma unroll
                for (int c = 0; c < 128; c += 4) {
                    float4 a = *(const float4*)&qs[qi][c];
                    float4 kk = *(const float4*)&ks[jj][c];
                    d += a.x * kk.x + a.y * kk.y + a.z * kk.z + a.w * kk.w;
                }
                s = d * 0.08838834764831845f; // 1/sqrt(128)
            }
            st[qi][jj] = s;
        }
        __syncthreads();
        float cmax = -30000.f;
#pragma unroll
        for (int j = 0; j < 32; ++j) cmax = fmaxf(cmax, st[qi][j]);
        float m_new = fmaxf(m_i, cmax);
        float alpha = __expf(m_i - m_new);
        l_i *= alpha;
#pragma unroll
        for (int d = 0; d < 8; ++d) acc[d] *= alpha;
        for (int j = 0; j < 32; ++j) {
            float pj = __expf(st[qi][j] - m_new);
            l_i += pj;
            float4 v0 = *(const float4*)&vs[j][dj * 8];
            float4 v1 = *(const float4*)&vs[j][dj * 8 + 4];
            acc[0] += pj * v0.x; acc[1] += pj * v0.y; acc[2] += pj * v0.z; acc[3] += pj * v0.w;
            acc[4] += pj * v1.x; acc[5] += pj * v1.y; acc[6] += pj * v1.z; acc[7] += pj * v1.w;
        }
        m_i = m_new;
    }
    int qrow = q0 + qi;
    if (qrow < LSEQ) {
        float inv = 1.f / l_i;
        size_t o = (size_t)(bl * LSEQ + qrow) * 512 + hh * 128 + dj * 8;
        unsigned int hw[4], lw[4];
#pragma unroll
        for (int i2 = 0; i2 < 4; ++i2) {
            unsigned short ha, hb, la, lb;
            f2split(acc[2 * i2] * inv, ha, la);
            f2split(acc[2 * i2 + 1] * inv, hb, lb);
            hw[i2] = (unsigned int)ha | ((unsigned int)hb << 16);
            lw[i2] = (unsigned int)la | ((unsigned int)lb << 16);
        }
        *(uint4*)(ctxh + o) = make_uint4(hw[0], hw[1], hw[2], hw[3]);
        *(uint4*)(ctxl + o) = make_uint4(lw[0], lw[1], lw[2], lw[3]);
    }
}

// ---------------------------------------------------------------- LayerNorm (in-place fp32; optional split-bf16 out)
__global__ __launch_bounds__(64) void ln_kernel(float* X, const float* __restrict__ gam,
                                                const float* __restrict__ bet,
                                                unsigned short* __restrict__ oh,
                                                unsigned short* __restrict__ ol) {
    const size_t row = blockIdx.x;
    const int tid = threadIdx.x;
    float* p = X + row * 512 + tid * 8;
    float4 v0 = *(float4*)p, v1 = *(float4*)(p + 4);
    float s = v0.x + v0.y + v0.z + v0.w + v1.x + v1.y + v1.z + v1.w;
#pragma unroll
    for (int off = 32; off; off >>= 1) s += __shfl_xor(s, off, 64);
    float mu = s * (1.f / 512.f);
    float d[8] = {v0.x - mu, v0.y - mu, v0.z - mu, v0.w - mu,
                  v1.x - mu, v1.y - mu, v1.z - mu, v1.w - mu};
    float s2 = 0.f;
#pragma unroll
    for (int i = 0; i < 8; ++i) s2 += d[i] * d[i];
#pragma unroll
    for (int off = 32; off; off >>= 1) s2 += __shfl_xor(s2, off, 64);
    float inv = 1.f / sqrtf(s2 * (1.f / 512.f) + 1e-5f);
    const float* gp = gam + tid * 8;
    const float* bp = bet + tid * 8;
    float4 g0 = *(const float4*)gp, g1 = *(const float4*)(gp + 4);
    float4 b0 = *(const float4*)bp, b1 = *(const float4*)(bp + 4);
    float y[8];
    y[0] = d[0] * inv * g0.x + b0.x; y[1] = d[1] * inv * g0.y + b0.y;
    y[2] = d[2] * inv * g0.z + b0.z; y[3] = d[3] * inv * g0.w + b0.w;
    y[4] = d[4] * inv * g1.x + b1.x; y[5] = d[5] * inv * g1.y + b1.y;
    y[6] = d[6] * inv * g1.z + b1.z; y[7] = d[7] * inv * g1.w + b1.w;
    *(float4*)p = make_float4(y[0], y[1], y[2], y[3]);
    *(float4*)(p + 4) = make_float4(y[4], y[5], y[6], y[7]);
    if (oh) {
        unsigned int hw[4], lw[4];
#pragma unroll
        for (int i2 = 0; i2 < 4; ++i2) {
            unsigned short ha, hb, la, lb;
            f2split(y[2 * i2], ha, la);
            f2split(y[2 * i2 + 1], hb, lb);
            hw[i2] = (unsigned int)ha | ((unsigned int)hb << 16);
            lw[i2] = (unsigned int)la | ((unsigned int)lb << 16);
        }
        size_t o = row * 512 + tid * 8;
        *(uint4*)(oh + o) = make_uint4(hw[0], hw[1], hw[2], hw[3]);
        *(uint4*)(ol + o) = make_uint4(lw[0], lw[1], lw[2], lw[3]);
    }
}

// ---------------------------------------------------------------- scatter outputs
__global__ void scatter_out(const float* __restrict__ seq, const int* __restrict__ ptr,
                            const int* __restrict__ mrn, const int* __restrict__ ms,
                            float* __restrict__ out_mol, float* __restrict__ out_node,
                            float* __restrict__ out_ring, int bBase, int CB) {
    int t = blockIdx.x * blockDim.x + threadIdx.x;
    int total = CB * LSEQ * 128;
    if (t >= total) return;
    int c4 = (t & 127) * 4;
    int row = t >> 7;
    int bl = row / LSEQ, p = row - bl * LSEQ;
    int b = bBase + bl;
    float4 v = *(const float4*)(seq + (size_t)row * 512 + c4);
    if (p == 0) {
        *(float4*)(out_mol + (size_t)b * 512 + c4) = v;
    } else if (p <= 128) {
        int i = p - 1;
        int nn = ptr[b + 1] - ptr[b];
        if (i < nn) *(float4*)(out_node + (size_t)(ptr[b] + i) * 512 + c4) = v;
    } else if (p >= 130 && p <= 137) {
        int i = p - 130;
        if (i < mrn[b]) *(float4*)(out_ring + (size_t)(ms[b] + i) * 512 + c4) = v;
    }
}

// ================================================================ host
extern "C" void kernel_launch(void* const* d_in, const int* in_sizes, int n_in,
                              void* d_out, int out_size, void* d_ws, size_t ws_size,
                              hipStream_t stream) {
    const float* x      = (const float*)d_in[0];
    const int*   ptr    = (const int*)d_in[1];
    const int*   rni    = (const int*)d_in[2];
    const int*   rnn    = (const int*)d_in[3];
    const int*   mrn    = (const int*)d_in[4];
    const float* CLS    = (const float*)d_in[5];
    const float* RINGt  = (const float*)d_in[6];
    const float* ENDt   = (const float*)d_in[7];
    const float* r_wqkv = (const float*)d_in[8];
    const float* r_bqkv = (const float*)d_in[9];
    const float* r_wo   = (const float*)d_in[10];
    const float* r_bo   = (const float*)d_in[11];
    const float* r_ln1g = (const float*)d_in[12];
    const float* r_ln1b = (const float*)d_in[13];
    const float* r_w1   = (const float*)d_in[14];
    const float* r_b1   = (const float*)d_in[15];
    const float* r_w2   = (const float*)d_in[16];
    const float* r_b2   = (const float*)d_in[17];
    const float* r_ln2g = (const float*)d_in[18];
    const float* r_ln2b = (const float*)d_in[19];
    const float* m_wqkv = (const float*)d_in[20];
    const float* m_bqkv = (const float*)d_in[21];
    const float* m_wo   = (const float*)d_in[22];
    const float* m_bo   = (const float*)d_in[23];
    const float* m_ln1g = (const float*)d_in[24];
    const float* m_ln1b = (const float*)d_in[25];
    const float* m_w1   = (const float*)d_in[26];
    const float* m_b1   = (const float*)d_in[27];
    const float* m_w2   = (const float*)d_in[28];
    const float* m_b2   = (const float*)d_in[29];
    const float* m_ln2g = (const float*)d_in[30];
    const float* m_ln2b = (const float*)d_in[31];

    const int N  = in_sizes[0] / D_;
    const int R  = in_sizes[3];
    const int Bm = in_sizes[4];

    // ------- workspace layout: [rings_vec][rs][ms][bf16 mol weights][bufA][bufQ][P0h][P0l]
    char* w = (char*)d_ws;
    size_t off = 0;
    float* rings_vec = (float*)(w + off); off += (size_t)R * 512 * 4;
    int* rs = (int*)(w + off); off += (size_t)R * 4;
    int* ms = (int*)(w + off); off += (size_t)Bm * 4;
    off = (off + 255) & ~(size_t)255;
    unsigned short* b_m_wqkv = (unsigned short*)(w + off);
    unsigned short* b_m_wo   = b_m_wqkv + 1536 * 512;
    unsigned short* b_m_w1   = b_m_wo   + 512 * 512;
    unsigned short* b_m_w2   = b_m_w1   + 1024 * 512;
    off += (size_t)(1536 * 512 + 512 * 512 + 1024 * 512 + 512 * 1024) * 2;
    off = (off + 255) & ~(size_t)255;

    size_t avail = (ws_size > off) ? (ws_size - off) : 0;
    const size_t perMolA = (size_t)LSEQ * 512 * 4;    // 284,672 fp32 residual/stream
    const size_t perMolQ = (size_t)LSEQ * 1536 * 4;   // 854,016 qkv (also hosts mol P1 split)
    const size_t perMolP = (size_t)LSEQ * 512 * 2;    // 142,336 each of P0h / P0l
    const size_t perMol  = perMolA + perMolQ + 2 * perMolP;  // 1,423,360
    int molChunk = (int)(avail / perMol);
    if (molChunk > Bm) molChunk = Bm;
    if (molChunk < 1) return; // workspace unusably small
    int ringChunk = molChunk * 17;   // ring rows are 8 vs 139 -> 17:1 fits all buffers
    if (ringChunk > R) ringChunk = R;
    float* bufA = (float*)(w + off); off += (size_t)molChunk * perMolA;
    float* bufQ = (float*)(w + off); off += (size_t)molChunk * perMolQ;
    unsigned short* P0h = (unsigned short*)(w + off);
    unsigned short* P0l = P0h + (size_t)molChunk * LSEQ * 512;
    // Ring-path fp32 ctx buffer reuses the P0 region: ringChunk*8*512*4 B
    //  = molChunk*278,528 <= 2*perMolP*molChunk = molChunk*284,672.
    float* bufC = (float*)P0h;
    // Mol P1 (w1 split output, N=1024) aliases bufQ (qkv dead after attention):
    // 2 * molChunk*139*1024*2 B = molChunk*569,344 <= molChunk*854,016.
    unsigned short* P1h = (unsigned short*)bufQ;
    unsigned short* P1l = P1h + (size_t)molChunk * LSEQ * 1024;

    float* out_mol  = (float*)d_out;
    float* out_node = out_mol + (size_t)Bm * 512;
    float* out_ring = out_node + (size_t)N * 512;

    scan_kernel<<<1, 256, 0, stream>>>(rnn, R, mrn, Bm, rs, ms);

    // ---------------- mol weight conversion (RNE; once per launch) ----------------
    convert_w<<<(1536 * 512 / 4 + 255) / 256, 256, 0, stream>>>(m_wqkv, b_m_wqkv, 1536 * 512 / 4);
    convert_w<<<(512 * 512 / 4 + 255) / 256, 256, 0, stream>>>(m_wo, b_m_wo, 512 * 512 / 4);
    convert_w<<<(1024 * 512 / 4 + 255) / 256, 256, 0, stream>>>(m_w1, b_m_w1, 1024 * 512 / 4);
    convert_w<<<(512 * 1024 / 4 + 255) / 256, 256, 0, stream>>>(m_w2, b_m_w2, 512 * 1024 / 4);

    // ---------------- ring encoder (chunked, fp32 path — bit-identical results) ----------------
    for (int r0 = 0; r0 < R; r0 += ringChunk) {
        int RC = (R - r0 < ringChunk) ? (R - r0) : ringChunk;
        int TrC = RC * LRING;
        build_xr<<<(TrC * 128 + 255) / 256, 256, 0, stream>>>(x, rni, rnn, rs, bufA, r0, RC);
        gemm_nt<false, false><<<dim3(1536 / 128, (TrC + 127) / 128), 256, 0, stream>>>(
            bufA, r_wqkv, r_bqkv, nullptr, bufQ, TrC, 1536, 512);
        ring_attn<<<dim3(2, RC), 256, 0, stream>>>(bufQ, rnn, bufC, r0);
        gemm_nt<false, true><<<dim3(512 / 128, (TrC + 127) / 128), 256, 0, stream>>>(
            bufC, r_wo, r_bo, bufA, bufA, TrC, 512, 512);
        ln_kernel<<<TrC, 64, 0, stream>>>(bufA, r_ln1g, r_ln1b, nullptr, nullptr);
        gemm_nt<true, false><<<dim3(1024 / 128, (TrC + 127) / 128), 256, 0, stream>>>(
            bufA, r_w1, r_b1, nullptr, bufQ, TrC, 1024, 512);
        gemm_nt<false, true><<<dim3(512 / 128, (TrC + 127) / 128), 256, 0, stream>>>(
            bufQ, r_w2, r_b2, bufA, bufA, TrC, 512, 1024);
        ln_kernel<<<TrC, 64, 0, stream>>>(bufA, r_ln2g, r_ln2b, nullptr, nullptr);
        argmax_pick<<<(RC * 512 + 255) / 256, 256, 0, stream>>>(bufA, rings_vec + (size_t)r0 * 512, RC);
    }

    // ---------------- molecule encoder (chunked, MFMA split-A path) ----------------
    for (int c0 = 0; c0 < Bm; c0 += molChunk) {
        int CB = (Bm - c0 < molChunk) ? (Bm - c0) : molChunk;
        int TmC = CB * LSEQ;
        build_seq<<<(TmC * 128 + 255) / 256, 256, 0, stream>>>(
            x, rings_vec, CLS, RINGt, ENDt, ptr, mrn, ms, bufA, P0h, P0l, c0, CB);
        gemm_bf16<false, false, false><<<dim3(1536 / 128, (TmC + 127) / 128), 256, 0, stream>>>(
            P0h, P0l, b_m_wqkv, m_bqkv, nullptr, bufQ, nullptr, nullptr, TmC, 1536, 512);
        {
            int Gpad = ((CB * 4 + 7) / 8) * 8;   // multiple of 8 => q-tiles of one
                                                 // (mol,head) share an XCD's L2
            mol_attn<<<dim3(Gpad, (LSEQ + 15) / 16), 256, 0, stream>>>(
                bufQ, ptr, mrn, P0h, P0l, c0, CB);
        }
        gemm_bf16<false, true, false><<<dim3(512 / 128, (TmC + 127) / 128), 256, 0, stream>>>(
            P0h, P0l, b_m_wo, m_bo, bufA, bufA, nullptr, nullptr, TmC, 512, 512);
        ln_kernel<<<TmC, 64, 0, stream>>>(bufA, m_ln1g, m_ln1b, P0h, P0l);
        gemm_bf16<true, false, true><<<dim3(1024 / 128, (TmC + 127) / 128), 256, 0, stream>>>(
            P0h, P0l, b_m_w1, m_b1, nullptr, nullptr, P1h, P1l, TmC, 1024, 512);
        gemm_bf16<false, true, false><<<dim3(512 / 128, (TmC + 127) / 128), 256, 0, stream>>>(
            P1h, P1l, b_m_w2, m_b2, bufA, bufA, nullptr, nullptr, TmC, 512, 1024);
        ln_kernel<<<TmC, 64, 0, stream>>>(bufA, m_ln2g, m_ln2b, nullptr, nullptr);
        scatter_out<<<(TmC * 128 + 255) / 256, 256, 0, stream>>>(
            bufA, ptr, mrn, ms, out_mol, out_node, out_ring, c0, CB);
    }
}

// Round 7
// 2899.294 us; speedup vs baseline: 1.5160x; 1.2226x over previous
//
#include <hip/hip_runtime.h>
#include <math.h>

// Problem constants (setup_inputs deterministic):
//   D=512, FF=1024, B=512 molecules, max nodes/mol=128, max rings/mol=8,
//   max nodes/ring=8, mol seq len = 1+128+1+8+1 = 139.
// Harness: fp32 buffers (values bf16-quantized), int32 index arrays.
//
// R7 = R6 with one bug fixed: the Pb pad-column zero-fill decoded the wave
// index as i>>6 (0..15, OOB for 8 waves) leaving rows 8..15 cols 144..159
// uninitialized -> fp16 garbage (NaN) entered PV's 5th k-step. Correct
// decode: w=i>>7, rest=i&127 (16 rows x 8 uint pairs per wave).
// mol_attn: MFMA fp16, block per (mol,head), K/V^T staged once to LDS.
// Ring path stays fp32 (argmax amplifier, R1); mol GEMMs split-A bf16 MFMA.
#define D_ 512
#define LSEQ 139
#define LRING 8
#define LDK 40   // LDS row stride in bf16 elems (80 B: 16B-aligned, conflict-free)

typedef __bf16 bf16x8 __attribute__((ext_vector_type(8)));
typedef float f32x4 __attribute__((ext_vector_type(4)));
typedef _Float16 f16x4 __attribute__((ext_vector_type(4)));
typedef _Float16 f16x8 __attribute__((ext_vector_type(8)));

__device__ __forceinline__ void f2split(float f, unsigned short& h, unsigned short& l) {
    unsigned int u = __float_as_uint(f);
    h = (unsigned short)(u >> 16);                       // truncated bf16 (exact if f is bf16)
    float r = f - __uint_as_float(u & 0xFFFF0000u);      // exact residual
    l = (unsigned short)(__float_as_uint(r) >> 16);      // truncated bf16 of residual
}

// ---------------------------------------------------------------- prefix sums
__global__ void scan_kernel(const int* __restrict__ rnn, int R,
                            const int* __restrict__ mrn, int Bm,
                            int* __restrict__ rs, int* __restrict__ ms) {
    __shared__ int lds[256];
    int tid = threadIdx.x;
    int chunk = (R + 255) / 256;
    int sum = 0;
    for (int i = 0; i < chunk; ++i) {
        int idx = tid * chunk + i;
        if (idx < R) sum += rnn[idx];
    }
    lds[tid] = sum;
    __syncthreads();
    if (tid == 0) {
        int run = 0;
        for (int t = 0; t < 256; ++t) { int tmp = lds[t]; lds[t] = run; run += tmp; }
    }
    __syncthreads();
    int off = lds[tid];
    for (int i = 0; i < chunk; ++i) {
        int idx = tid * chunk + i;
        if (idx < R) { rs[idx] = off; off += rnn[idx]; }
    }
    __syncthreads();
    chunk = (Bm + 255) / 256;
    sum = 0;
    for (int i = 0; i < chunk; ++i) {
        int idx = tid * chunk + i;
        if (idx < Bm) sum += mrn[idx];
    }
    __syncthreads();
    lds[tid] = sum;
    __syncthreads();
    if (tid == 0) {
        int run = 0;
        for (int t = 0; t < 256; ++t) { int tmp = lds[t]; lds[t] = run; run += tmp; }
    }
    __syncthreads();
    off = lds[tid];
    for (int i = 0; i < chunk; ++i) {
        int idx = tid * chunk + i;
        if (idx < Bm) { ms[idx] = off; off += mrn[idx]; }
    }
}

// ---------------------------------------------------------------- fp32 -> bf16 weight convert (RNE; identity on bf16-exact values)
__global__ void convert_w(const float* __restrict__ src, unsigned short* __restrict__ dst, int n4) {
    int t = blockIdx.x * blockDim.x + threadIdx.x;
    if (t >= n4) return;
    const float4 v = *(const float4*)(src + (size_t)t * 4);
    unsigned int u0 = __float_as_uint(v.x), u1 = __float_as_uint(v.y),
                 u2 = __float_as_uint(v.z), u3 = __float_as_uint(v.w);
    u0 = (u0 + 0x7FFFu + ((u0 >> 16) & 1)) >> 16;
    u1 = (u1 + 0x7FFFu + ((u1 >> 16) & 1)) >> 16;
    u2 = (u2 + 0x7FFFu + ((u2 >> 16) & 1)) >> 16;
    u3 = (u3 + 0x7FFFu + ((u3 >> 16) & 1)) >> 16;
    *(uint2*)(dst + (size_t)t * 4) = make_uint2(u0 | (u1 << 16), u2 | (u3 << 16));
}

// ---------------------------------------------------------------- gather ring inputs (padded), fp32 (ring path)
__global__ void build_xr(const float* __restrict__ x, const int* __restrict__ rni,
                         const int* __restrict__ rnn, const int* __restrict__ rs,
                         float* __restrict__ out, int rBase, int RC) {
    int t = blockIdx.x * blockDim.x + threadIdx.x;
    int total = RC * LRING * (D_ / 4);
    if (t >= total) return;
    int c4 = (t & 127) * 4;
    int row = t >> 7;                 // local row
    int rl = row >> 3, l = row & 7;
    int r = rBase + rl;
    float4 v = make_float4(0.f, 0.f, 0.f, 0.f);
    if (l < rnn[r]) {
        int node = rni[rs[r] + l];
        v = *(const float4*)(x + (size_t)node * D_ + c4);
    }
    *(float4*)(out + (size_t)row * D_ + c4) = v;
}

// ---------------------------------------------------------------- fp32 GEMM-NT (ring path), 128x128 tile, 8x8 register block.
// Per-output k-accumulation strictly sequential -> bit-identical results.
// C[M,N] = A[M,K] * Bw[N,K]^T + bias (+Res) (+relu).  Res/C may alias.
template <bool RELU, bool RES>
__global__ __launch_bounds__(256) void gemm_nt(const float* __restrict__ A,
                                               const float* __restrict__ Bw,
                                               const float* __restrict__ bias,
                                               const float* Res, float* C,
                                               int M, int N, int K) {
    __shared__ __align__(16) float As[16][132];
    __shared__ __align__(16) float Bs[16][132];
    const int bm = blockIdx.y * 128, bn = blockIdx.x * 128;
    const int tid = threadIdx.x;
    const int ty = tid >> 4, tx = tid & 15;   // 16x16 threads, 8x8 outputs each
    const int sr = tid >> 1;                  // staging row 0..127
    const int sc = (tid & 1) * 8;             // staging k sub-col 0 or 8
    float acc[8][8];
#pragma unroll
    for (int i = 0; i < 8; ++i)
#pragma unroll
        for (int j = 0; j < 8; ++j) acc[i][j] = 0.f;
    const float4 z4 = make_float4(0.f, 0.f, 0.f, 0.f);
    const int arow = bm + sr;
    const bool aok = arow < M;
    for (int k0 = 0; k0 < K; k0 += 16) {
        float4 av0 = z4, av1 = z4;
        if (aok) {
            av0 = *(const float4*)(A + (size_t)arow * K + k0 + sc);
            av1 = *(const float4*)(A + (size_t)arow * K + k0 + sc + 4);
        }
        const float4 bv0 = *(const float4*)(Bw + (size_t)(bn + sr) * K + k0 + sc); // N%128==0 always
        const float4 bv1 = *(const float4*)(Bw + (size_t)(bn + sr) * K + k0 + sc + 4);
        __syncthreads();
        As[sc + 0][sr] = av0.x; As[sc + 1][sr] = av0.y; As[sc + 2][sr] = av0.z; As[sc + 3][sr] = av0.w;
        As[sc + 4][sr] = av1.x; As[sc + 5][sr] = av1.y; As[sc + 6][sr] = av1.z; As[sc + 7][sr] = av1.w;
        Bs[sc + 0][sr] = bv0.x; Bs[sc + 1][sr] = bv0.y; Bs[sc + 2][sr] = bv0.z; Bs[sc + 3][sr] = bv0.w;
        Bs[sc + 4][sr] = bv1.x; Bs[sc + 5][sr] = bv1.y; Bs[sc + 6][sr] = bv1.z; Bs[sc + 7][sr] = bv1.w;
        __syncthreads();
#pragma unroll
        for (int k = 0; k < 16; ++k) {
            float a[8], b[8];
            *(float4*)&a[0] = *(const float4*)&As[k][ty * 8];
            *(float4*)&a[4] = *(const float4*)&As[k][ty * 8 + 4];
            *(float4*)&b[0] = *(const float4*)&Bs[k][tx * 8];
            *(float4*)&b[4] = *(const float4*)&Bs[k][tx * 8 + 4];
#pragma unroll
            for (int i = 0; i < 8; ++i)
#pragma unroll
                for (int j = 0; j < 8; ++j) acc[i][j] += a[i] * b[j];
        }
    }
    const int n = bn + tx * 8;
    float bvv[8];
    *(float4*)&bvv[0] = *(const float4*)(bias + n);
    *(float4*)&bvv[4] = *(const float4*)(bias + n + 4);
#pragma unroll
    for (int i = 0; i < 8; ++i) {
        int m = bm + ty * 8 + i;
        if (m >= M) continue;
        float r[8];
#pragma unroll
        for (int j = 0; j < 8; ++j) r[j] = acc[i][j] + bvv[j];
        if (RES) {
            float rv[8];
            *(float4*)&rv[0] = *(const float4*)(Res + (size_t)m * N + n);
            *(float4*)&rv[4] = *(const float4*)(Res + (size_t)m * N + n + 4);
#pragma unroll
            for (int j = 0; j < 8; ++j) r[j] += rv[j];
        }
        if (RELU) {
#pragma unroll
            for (int j = 0; j < 8; ++j) r[j] = fmaxf(r[j], 0.f);
        }
        *(float4*)(C + (size_t)m * N + n) = make_float4(r[0], r[1], r[2], r[3]);
        *(float4*)(C + (size_t)m * N + n + 4) = make_float4(r[4], r[5], r[6], r[7]);
    }
}

// ---------------------------------------------------------------- split-A bf16 MFMA GEMM-NT (mol path):
// C[M,N] = (Ah+Al)[M,K] * Bw[N,K]^T + bias (+Res fp32) (+relu).
// OSPLIT: write output as split bf16 (Oh/Ol) instead of fp32 C.
// 128x128 tile, 4 waves (2x2), mfma_f32_16x16x32_bf16, 2 MFMA per fragment.
template <bool RELU, bool RES, bool OSPLIT>
__global__ __launch_bounds__(256, 2) void gemm_bf16(
        const unsigned short* __restrict__ Ah, const unsigned short* __restrict__ Al,
        const unsigned short* __restrict__ Bw, const float* __restrict__ bias,
        const float* __restrict__ Res, float* __restrict__ C,
        unsigned short* __restrict__ Oh, unsigned short* __restrict__ Ol,
        int M, int N, int K) {
    __shared__ __align__(16) unsigned short sAh[128][LDK];
    __shared__ __align__(16) unsigned short sAl[128][LDK];
    __shared__ __align__(16) unsigned short sB[128][LDK];
    const int bm = blockIdx.y * 128, bn = blockIdx.x * 128;
    const int tid = threadIdx.x;
    const int lane = tid & 63, wid = tid >> 6;
    const int wr = wid >> 1, wc = wid & 1;        // wave grid 2x2, wave tile 64x64
    const int fr = lane & 15, fq = lane >> 4;     // fragment row/col + k-quad
    const int sr = tid >> 2;                      // staging row 0..63 (and +64)
    const int sc = (tid & 3) * 8;                 // staging k sub-col 0,8,16,24 (8 bf16 = 16B)
    f32x4 acc[4][4];
#pragma unroll
    for (int m = 0; m < 4; ++m)
#pragma unroll
        for (int n = 0; n < 4; ++n) {
            acc[m][n][0] = 0.f; acc[m][n][1] = 0.f;
            acc[m][n][2] = 0.f; acc[m][n][3] = 0.f;
        }
    const int r0 = bm + sr, r1 = r0 + 64;
    const bool ok0 = r0 < M, ok1 = r1 < M;
    for (int k0 = 0; k0 < K; k0 += 32) {
        uint4 a0 = make_uint4(0, 0, 0, 0), a1 = a0, al0 = a0, al1 = a0;
        if (ok0) {
            a0  = *(const uint4*)(Ah + (size_t)r0 * K + k0 + sc);
            al0 = *(const uint4*)(Al + (size_t)r0 * K + k0 + sc);
        }
        if (ok1) {
            a1  = *(const uint4*)(Ah + (size_t)r1 * K + k0 + sc);
            al1 = *(const uint4*)(Al + (size_t)r1 * K + k0 + sc);
        }
        const uint4 b0 = *(const uint4*)(Bw + (size_t)(bn + sr) * K + k0 + sc);
        const uint4 b1 = *(const uint4*)(Bw + (size_t)(bn + sr + 64) * K + k0 + sc);
        __syncthreads();
        *(uint4*)&sAh[sr][sc] = a0;  *(uint4*)&sAh[sr + 64][sc] = a1;
        *(uint4*)&sAl[sr][sc] = al0; *(uint4*)&sAl[sr + 64][sc] = al1;
        *(uint4*)&sB[sr][sc]  = b0;  *(uint4*)&sB[sr + 64][sc]  = b1;
        __syncthreads();
        bf16x8 bfr[4];
#pragma unroll
        for (int n = 0; n < 4; ++n)
            bfr[n] = *(const bf16x8*)&sB[wc * 64 + n * 16 + fr][fq * 8];
#pragma unroll
        for (int m = 0; m < 4; ++m) {
            bf16x8 ah = *(const bf16x8*)&sAh[wr * 64 + m * 16 + fr][fq * 8];
            bf16x8 al = *(const bf16x8*)&sAl[wr * 64 + m * 16 + fr][fq * 8];
#pragma unroll
            for (int n = 0; n < 4; ++n)
                acc[m][n] = __builtin_amdgcn_mfma_f32_16x16x32_bf16(ah, bfr[n], acc[m][n], 0, 0, 0);
#pragma unroll
            for (int n = 0; n < 4; ++n)
                acc[m][n] = __builtin_amdgcn_mfma_f32_16x16x32_bf16(al, bfr[n], acc[m][n], 0, 0, 0);
        }
    }
    // epilogue: C/D layout col = lane&15, row = (lane>>4)*4 + reg  [m89-verified]
    float bv[4];
#pragma unroll
    for (int n = 0; n < 4; ++n) bv[n] = bias[bn + wc * 64 + n * 16 + fr];
#pragma unroll
    for (int m = 0; m < 4; ++m) {
#pragma unroll
        for (int i = 0; i < 4; ++i) {
            int row = bm + wr * 64 + m * 16 + fq * 4 + i;
            if (row >= M) continue;
#pragma unroll
            for (int n = 0; n < 4; ++n) {
                int col = bn + wc * 64 + n * 16 + fr;
                float v = acc[m][n][i] + bv[n];
                if (RES) v += Res[(size_t)row * N + col];
                if (RELU) v = fmaxf(v, 0.f);
                if (OSPLIT) {
                    unsigned short h, l;
                    f2split(v, h, l);
                    Oh[(size_t)row * N + col] = h;
                    Ol[(size_t)row * N + col] = l;
                } else {
                    C[(size_t)row * N + col] = v;
                }
            }
        }
    }
}

// ---------------------------------------------------------------- ring attention: block per (head, local ring). L=8, dh=256, h=2.
__global__ __launch_bounds__(256) void ring_attn(const float* __restrict__ qkv,
                                                 const int* __restrict__ rnn,
                                                 float* __restrict__ ctx, int rBase) {
    __shared__ float qs[8][260], ks[8][260], vs[8][260];
    __shared__ float sS[8][8];
    __shared__ float pS[8][8];
    const int hh = blockIdx.x;
    const int rl = blockIdx.y;
    const int tid = threadIdx.x;
    const int rn = rnn[rBase + rl];
    const float* base = qkv + (size_t)rl * 8 * 1536;
    for (int i = tid; i < 8 * 256; i += 256) {
        int l = i >> 8, c = i & 255;
        const float* p = base + (size_t)l * 1536 + hh * 256 + c;
        qs[l][c] = p[0];
        ks[l][c] = p[512];
        vs[l][c] = p[1024];
    }
    __syncthreads();
    if (tid < 64) {
        int i = tid >> 3, j = tid & 7;
        float s = -30000.f;
        if (j < rn) {
            float d = 0.f;
            for (int c = 0; c < 256; ++c) d += qs[i][c] * ks[j][c];
            s = d * 0.0625f; // 1/sqrt(256)
        }
        sS[i][j] = s;
    }
    __syncthreads();
    if (tid < 8) {
        int i = tid;
        float mx = -30000.f;
#pragma unroll
        for (int j = 0; j < 8; ++j) mx = fmaxf(mx, sS[i][j]);
        float p[8], sum = 0.f;
#pragma unroll
        for (int j = 0; j < 8; ++j) { p[j] = __expf(sS[i][j] - mx); sum += p[j]; }
        float inv = 1.f / sum;
#pragma unroll
        for (int j = 0; j < 8; ++j) pS[i][j] = p[j] * inv;
    }
    __syncthreads();
    {
        int d = tid;
#pragma unroll
        for (int i = 0; i < 8; ++i) {
            float a = 0.f;
#pragma unroll
            for (int j = 0; j < 8; ++j) a += pS[i][j] * vs[j][d];
            ctx[(size_t)(rl * 8 + i) * 512 + hh * 256 + d] = a;
        }
    }
}

// ---------------------------------------------------------------- argmax(|Xe|) over 8 positions -> rings_vec
__global__ void argmax_pick(const float* __restrict__ Xe, float* __restrict__ rv, int RC) {
    int t = blockIdx.x * blockDim.x + threadIdx.x;
    if (t >= RC * 512) return;
    int r = t >> 9, d = t & 511;
    const float* p = Xe + (size_t)r * 8 * 512 + d;
    float best = fabsf(p[0]);
    int pos = 0;
#pragma unroll
    for (int l = 1; l < 8; ++l) {
        float v = fabsf(p[(size_t)l * 512]);
        if (v > best) { best = v; pos = l; } // strict > == first-occurrence tie-break
    }
    rv[t] = p[(size_t)pos * 512];
}

// ---------------------------------------------------------------- build mol sequence [CLS, nodes.., RING, rings.., END], fp32 + split
__global__ void build_seq(const float* __restrict__ x, const float* __restrict__ rv,
                          const float* __restrict__ CLS, const float* __restrict__ RING,
                          const float* __restrict__ END, const int* __restrict__ ptr,
                          const int* __restrict__ mrn, const int* __restrict__ ms,
                          float* __restrict__ seq, unsigned short* __restrict__ oh,
                          unsigned short* __restrict__ ol, int bBase, int CB) {
    int t = blockIdx.x * blockDim.x + threadIdx.x;
    int total = CB * LSEQ * 128;
    if (t >= total) return;
    int c4 = (t & 127) * 4;
    int row = t >> 7;
    int bl = row / LSEQ, p = row - bl * LSEQ;
    int b = bBase + bl;
    const float* src = nullptr;
    if (p == 0) src = CLS;
    else if (p <= 128) {
        int i = p - 1;
        int nn = ptr[b + 1] - ptr[b];
        if (i < nn) src = x + (size_t)(ptr[b] + i) * 512;
    } else if (p == 129) src = RING;
    else if (p <= 137) {
        int i = p - 130;
        if (i < mrn[b]) src = rv + (size_t)(ms[b] + i) * 512;
    } else src = END;
    float4 v = src ? *(const float4*)(src + c4) : make_float4(0.f, 0.f, 0.f, 0.f);
    *(float4*)(seq + (size_t)row * 512 + c4) = v;
    unsigned short h0, h1, h2, h3, l0, l1, l2, l3;
    f2split(v.x, h0, l0); f2split(v.y, h1, l1);
    f2split(v.z, h2, l2); f2split(v.w, h3, l3);
    *(uint2*)(oh + (size_t)row * 512 + c4) = make_uint2(h0 | (h1 << 16), h2 | (h3 << 16));
    *(uint2*)(ol + (size_t)row * 512 + c4) = make_uint2(l0 | (l1 << 16), l2 | (l3 << 16));
}

// ---------------------------------------------------------------- mol attention. L=139, dh=128, h=4.
// MFMA fp16. Block per (mol,head), 512 thr / 8 waves. K row-major and V
// TRANSPOSED staged once to LDS as fp16; per-wave q-tiles (9/8); S = QK^T via
// mfma NT (A=Q rows, B=K rows); full-row softmax in regs; P -> per-wave LDS
// fp16; O = P*V via mfma NT (A=P rows, B=Vt rows). kj padded 139->160.
__device__ __forceinline__ bool key_valid_mol(int j, int nn, int nr) {
    if (j == 0 || j == 129 || j == 138) return true;
    if (j <= 128) return (j - 1) < nn;
    if (j <= 137) return (j - 130) < nr;
    return false;
}

__global__ __launch_bounds__(512, 1) void mol_attn(const float* __restrict__ qkv,
                                                   const int* __restrict__ ptr,
                                                   const int* __restrict__ mrn,
                                                   unsigned short* __restrict__ ctxh,
                                                   unsigned short* __restrict__ ctxl,
                                                   int bBase) {
    __shared__ __align__(16) _Float16 Ksh[144][136];   // [kj][d]    39,168 B
    __shared__ __align__(16) _Float16 Vt[128][168];    // [d][kj]    43,008 B
    __shared__ __align__(16) _Float16 Pb[8][16][168];  // per-wave P 43,008 B
    const int hh = blockIdx.x, bl = blockIdx.y;
    const int b = bBase + bl;
    const int tid = threadIdx.x;
    const int nn = ptr[b + 1] - ptr[b];
    const int nr = mrn[b];
    const float* base = qkv + (size_t)bl * LSEQ * 1536;
    // ---- stage K (row-major) and V (transposed) once, fp32 -> fp16 RNE
    for (int i = tid; i < LSEQ * 32; i += 512) {
        int row = i >> 5, c4 = (i & 31) * 4;
        const float* pk = base + (size_t)row * 1536 + 512 + hh * 128 + c4;
        float4 kk = *(const float4*)pk;
        float4 vv = *(const float4*)(pk + 512);
        f16x4 kp;
        kp[0] = (_Float16)kk.x; kp[1] = (_Float16)kk.y;
        kp[2] = (_Float16)kk.z; kp[3] = (_Float16)kk.w;
        *(f16x4*)&Ksh[row][c4] = kp;
        Vt[c4 + 0][row] = (_Float16)vv.x;
        Vt[c4 + 1][row] = (_Float16)vv.y;
        Vt[c4 + 2][row] = (_Float16)vv.z;
        Vt[c4 + 3][row] = (_Float16)vv.w;
    }
    // zero pads: K rows 139..143 (read by QK B-frags, masked later but must be finite)
    for (int i = tid; i < 5 * 68; i += 512) {
        int r = 139 + i / 68, c = (i % 68) * 2;
        *(unsigned int*)&Ksh[r][c] = 0u;
    }
    // Vt cols 139..159 (read by PV with P=0; must be finite)
    for (int i = tid; i < 128 * 21; i += 512) {
        Vt[i / 21][139 + (i % 21)] = (_Float16)0.f;
    }
    // P cols 144..159 for ALL 8 waves x 16 rows (read by PV kstep 4).
    // R6 BUG was w=i>>6 (0..15, OOB). Correct: 128 items per wave (16 rows x 8 uints).
    for (int i = tid; i < 8 * 16 * 8; i += 512) {
        int w = i >> 7, rest = i & 127;
        int r = rest >> 3, c = 144 + (rest & 7) * 2;
        *(unsigned int*)&Pb[w][r][c] = 0u;
    }
    __syncthreads();
    const int wid = tid >> 6, lane = tid & 63;
    const int g = lane >> 4, cc = lane & 15;
    bool valid[9];
#pragma unroll
    for (int t = 0; t < 9; ++t) valid[t] = key_valid_mol(t * 16 + cc, nn, nr);
    const float scale = 0.08838834764831845f; // 1/sqrt(128)
    for (int qt = wid; qt < 9; qt += 8) {
        const int q0 = qt * 16;
        // ---- Q fragments from global (A-operand: row=lane&15, 8 d at g*8+32ks)
        f16x8 qf[4];
        {
            int qrow = q0 + cc; if (qrow > LSEQ - 1) qrow = LSEQ - 1;
            const float* qp = base + (size_t)qrow * 1536 + hh * 128 + g * 8;
#pragma unroll
            for (int ks = 0; ks < 4; ++ks) {
                float4 a = *(const float4*)(qp + 32 * ks);
                float4 c2 = *(const float4*)(qp + 32 * ks + 4);
                f16x8 q8;
                q8[0] = (_Float16)a.x;  q8[1] = (_Float16)a.y;
                q8[2] = (_Float16)a.z;  q8[3] = (_Float16)a.w;
                q8[4] = (_Float16)c2.x; q8[5] = (_Float16)c2.y;
                q8[6] = (_Float16)c2.z; q8[7] = (_Float16)c2.w;
                qf[ks] = q8;
            }
        }
        // ---- S = Q K^T : 9 kj-tiles x 4 d-ksteps
        f32x4 sa[9];
#pragma unroll
        for (int kt = 0; kt < 9; ++kt) {
            f32x4 acc = {0.f, 0.f, 0.f, 0.f};
#pragma unroll
            for (int ks = 0; ks < 4; ++ks) {
                f16x8 kf = *(const f16x8*)&Ksh[kt * 16 + cc][g * 8 + 32 * ks];
                acc = __builtin_amdgcn_mfma_f32_16x16x32_f16(qf[ks], kf, acc, 0, 0, 0);
            }
            sa[kt] = acc;
        }
        // ---- mask + scale ; row max (row = g*4+r, cols spread over lane&15 and kt)
        float m4[4] = {-30000.f, -30000.f, -30000.f, -30000.f};
#pragma unroll
        for (int kt = 0; kt < 9; ++kt)
#pragma unroll
            for (int r = 0; r < 4; ++r) {
                float s = valid[kt] ? sa[kt][r] * scale : -30000.f;
                sa[kt][r] = s;
                m4[r] = fmaxf(m4[r], s);
            }
#pragma unroll
        for (int r = 0; r < 4; ++r) {
            m4[r] = fmaxf(m4[r], __shfl_xor(m4[r], 1, 64));
            m4[r] = fmaxf(m4[r], __shfl_xor(m4[r], 2, 64));
            m4[r] = fmaxf(m4[r], __shfl_xor(m4[r], 4, 64));
            m4[r] = fmaxf(m4[r], __shfl_xor(m4[r], 8, 64));
        }
        // ---- P = exp(S-m), row sums
        float l4[4] = {0.f, 0.f, 0.f, 0.f};
#pragma unroll
        for (int kt = 0; kt < 9; ++kt)
#pragma unroll
            for (int r = 0; r < 4; ++r) {
                float p = __expf(sa[kt][r] - m4[r]);
                sa[kt][r] = p;
                l4[r] += p;
            }
#pragma unroll
        for (int r = 0; r < 4; ++r) {
            l4[r] += __shfl_xor(l4[r], 1, 64);
            l4[r] += __shfl_xor(l4[r], 2, 64);
            l4[r] += __shfl_xor(l4[r], 4, 64);
            l4[r] += __shfl_xor(l4[r], 8, 64);
        }
        // ---- P -> per-wave LDS (fp16).  [qi][kj]: qi=g*4+r, kj=cc+16*kt
#pragma unroll
        for (int kt = 0; kt < 9; ++kt)
#pragma unroll
            for (int r = 0; r < 4; ++r)
                Pb[wid][g * 4 + r][cc + 16 * kt] = (_Float16)sa[kt][r];
        // ---- O = P V : A=P rows (qi), B=Vt rows (d), contract kj (5 ksteps of 32)
        f16x8 pf[5];
#pragma unroll
        for (int ks = 0; ks < 5; ++ks)
            pf[ks] = *(const f16x8*)&Pb[wid][cc][g * 8 + 32 * ks];
        f32x4 oacc[8];
#pragma unroll
        for (int dt = 0; dt < 8; ++dt) {
            f32x4 acc = {0.f, 0.f, 0.f, 0.f};
#pragma unroll
            for (int ks = 0; ks < 5; ++ks) {
                f16x8 vf = *(const f16x8*)&Vt[dt * 16 + cc][g * 8 + 32 * ks];
                acc = __builtin_amdgcn_mfma_f32_16x16x32_f16(pf[ks], vf, acc, 0, 0, 0);
            }
            oacc[dt] = acc;
        }
        // ---- normalize + split-bf16 store.  C-layout: col=lane&15=d_local, row=g*4+r=qi_local
        float inv[4];
#pragma unroll
        for (int r = 0; r < 4; ++r) inv[r] = 1.f / l4[r];
#pragma unroll
        for (int r = 0; r < 4; ++r) {
            int qi = q0 + g * 4 + r;
            if (qi < LSEQ) {
                size_t o = (size_t)(bl * LSEQ + qi) * 512 + hh * 128 + cc;
#pragma unroll
                for (int dt = 0; dt < 8; ++dt) {
                    unsigned short h, l;
                    f2split(oacc[dt][r] * inv[r], h, l);
                    ctxh[o + dt * 16] = h;
                    ctxl[o + dt * 16] = l;
                }
            }
        }
    }
}

// ---------------------------------------------------------------- LayerNorm (in-place fp32; optional split-bf16 out)
__global__ __launch_bounds__(64) void ln_kernel(float* X, const float* __restrict__ gam,
                                                const float* __restrict__ bet,
                                                unsigned short* __restrict__ oh,
                                                unsigned short* __restrict__ ol) {
    const size_t row = blockIdx.x;
    const int tid = threadIdx.x;
    float* p = X + row * 512 + tid * 8;
    float4 v0 = *(float4*)p, v1 = *(float4*)(p + 4);
    float s = v0.x + v0.y + v0.z + v0.w + v1.x + v1.y + v1.z + v1.w;
#pragma unroll
    for (int off = 32; off; off >>= 1) s += __shfl_xor(s, off, 64);
    float mu = s * (1.f / 512.f);
    float d[8] = {v0.x - mu, v0.y - mu, v0.z - mu, v0.w - mu,
                  v1.x - mu, v1.y - mu, v1.z - mu, v1.w - mu};
    float s2 = 0.f;
#pragma unroll
    for (int i = 0; i < 8; ++i) s2 += d[i] * d[i];
#pragma unroll
    for (int off = 32; off; off >>= 1) s2 += __shfl_xor(s2, off, 64);
    float inv = 1.f / sqrtf(s2 * (1.f / 512.f) + 1e-5f);
    const float* gp = gam + tid * 8;
    const float* bp = bet + tid * 8;
    float4 g0 = *(const float4*)gp, g1 = *(const float4*)(gp + 4);
    float4 b0 = *(const float4*)bp, b1 = *(const float4*)(bp + 4);
    float y[8];
    y[0] = d[0] * inv * g0.x + b0.x; y[1] = d[1] * inv * g0.y + b0.y;
    y[2] = d[2] * inv * g0.z + b0.z; y[3] = d[3] * inv * g0.w + b0.w;
    y[4] = d[4] * inv * g1.x + b1.x; y[5] = d[5] * inv * g1.y + b1.y;
    y[6] = d[6] * inv * g1.z + b1.z; y[7] = d[7] * inv * g1.w + b1.w;
    *(float4*)p = make_float4(y[0], y[1], y[2], y[3]);
    *(float4*)(p + 4) = make_float4(y[4], y[5], y[6], y[7]);
    if (oh) {
        unsigned int hw[4], lw[4];
#pragma unroll
        for (int i2 = 0; i2 < 4; ++i2) {
            unsigned short ha, hb, la, lb;
            f2split(y[2 * i2], ha, la);
            f2split(y[2 * i2 + 1], hb, lb);
            hw[i2] = (unsigned int)ha | ((unsigned int)hb << 16);
            lw[i2] = (unsigned int)la | ((unsigned int)lb << 16);
        }
        size_t o = row * 512 + tid * 8;
        *(uint4*)(oh + o) = make_uint4(hw[0], hw[1], hw[2], hw[3]);
        *(uint4*)(ol + o) = make_uint4(lw[0], lw[1], lw[2], lw[3]);
    }
}

// ---------------------------------------------------------------- scatter outputs
__global__ void scatter_out(const float* __restrict__ seq, const int* __restrict__ ptr,
                            const int* __restrict__ mrn, const int* __restrict__ ms,
                            float* __restrict__ out_mol, float* __restrict__ out_node,
                            float* __restrict__ out_ring, int bBase, int CB) {
    int t = blockIdx.x * blockDim.x + threadIdx.x;
    int total = CB * LSEQ * 128;
    if (t >= total) return;
    int c4 = (t & 127) * 4;
    int row = t >> 7;
    int bl = row / LSEQ, p = row - bl * LSEQ;
    int b = bBase + bl;
    float4 v = *(const float4*)(seq + (size_t)row * 512 + c4);
    if (p == 0) {
        *(float4*)(out_mol + (size_t)b * 512 + c4) = v;
    } else if (p <= 128) {
        int i = p - 1;
        int nn = ptr[b + 1] - ptr[b];
        if (i < nn) *(float4*)(out_node + (size_t)(ptr[b] + i) * 512 + c4) = v;
    } else if (p >= 130 && p <= 137) {
        int i = p - 130;
        if (i < mrn[b]) *(float4*)(out_ring + (size_t)(ms[b] + i) * 512 + c4) = v;
    }
}

// ================================================================ host
extern "C" void kernel_launch(void* const* d_in, const int* in_sizes, int n_in,
                              void* d_out, int out_size, void* d_ws, size_t ws_size,
                              hipStream_t stream) {
    const float* x      = (const float*)d_in[0];
    const int*   ptr    = (const int*)d_in[1];
    const int*   rni    = (const int*)d_in[2];
    const int*   rnn    = (const int*)d_in[3];
    const int*   mrn    = (const int*)d_in[4];
    const float* CLS    = (const float*)d_in[5];
    const float* RINGt  = (const float*)d_in[6];
    const float* ENDt   = (const float*)d_in[7];
    const float* r_wqkv = (const float*)d_in[8];
    const float* r_bqkv = (const float*)d_in[9];
    const float* r_wo   = (const float*)d_in[10];
    const float* r_bo   = (const float*)d_in[11];
    const float* r_ln1g = (const float*)d_in[12];
    const float* r_ln1b = (const float*)d_in[13];
    const float* r_w1   = (const float*)d_in[14];
    const float* r_b1   = (const float*)d_in[15];
    const float* r_w2   = (const float*)d_in[16];
    const float* r_b2   = (const float*)d_in[17];
    const float* r_ln2g = (const float*)d_in[18];
    const float* r_ln2b = (const float*)d_in[19];
    const float* m_wqkv = (const float*)d_in[20];
    const float* m_bqkv = (const float*)d_in[21];
    const float* m_wo   = (const float*)d_in[22];
    const float* m_bo   = (const float*)d_in[23];
    const float* m_ln1g = (const float*)d_in[24];
    const float* m_ln1b = (const float*)d_in[25];
    const float* m_w1   = (const float*)d_in[26];
    const float* m_b1   = (const float*)d_in[27];
    const float* m_w2   = (const float*)d_in[28];
    const float* m_b2   = (const float*)d_in[29];
    const float* m_ln2g = (const float*)d_in[30];
    const float* m_ln2b = (const float*)d_in[31];

    const int N  = in_sizes[0] / D_;
    const int R  = in_sizes[3];
    const int Bm = in_sizes[4];

    // ------- workspace layout: [rings_vec][rs][ms][bf16 mol weights][bufA][bufQ][P0h][P0l]
    char* w = (char*)d_ws;
    size_t off = 0;
    float* rings_vec = (float*)(w + off); off += (size_t)R * 512 * 4;
    int* rs = (int*)(w + off); off += (size_t)R * 4;
    int* ms = (int*)(w + off); off += (size_t)Bm * 4;
    off = (off + 255) & ~(size_t)255;
    unsigned short* b_m_wqkv = (unsigned short*)(w + off);
    unsigned short* b_m_wo   = b_m_wqkv + 1536 * 512;
    unsigned short* b_m_w1   = b_m_wo   + 512 * 512;
    unsigned short* b_m_w2   = b_m_w1   + 1024 * 512;
    off += (size_t)(1536 * 512 + 512 * 512 + 1024 * 512 + 512 * 1024) * 2;
    off = (off + 255) & ~(size_t)255;

    size_t avail = (ws_size > off) ? (ws_size - off) : 0;
    const size_t perMolA = (size_t)LSEQ * 512 * 4;    // 284,672 fp32 residual/stream
    const size_t perMolQ = (size_t)LSEQ * 1536 * 4;   // 854,016 qkv (also hosts mol P1 split)
    const size_t perMolP = (size_t)LSEQ * 512 * 2;    // 142,336 each of P0h / P0l
    const size_t perMol  = perMolA + perMolQ + 2 * perMolP;  // 1,423,360
    int molChunk = (int)(avail / perMol);
    if (molChunk > Bm) molChunk = Bm;
    if (molChunk < 1) return; // workspace unusably small
    int ringChunk = molChunk * 17;   // ring rows are 8 vs 139 -> 17:1 fits all buffers
    if (ringChunk > R) ringChunk = R;
    float* bufA = (float*)(w + off); off += (size_t)molChunk * perMolA;
    float* bufQ = (float*)(w + off); off += (size_t)molChunk * perMolQ;
    unsigned short* P0h = (unsigned short*)(w + off);
    unsigned short* P0l = P0h + (size_t)molChunk * LSEQ * 512;
    // Ring-path fp32 ctx buffer reuses the P0 region: ringChunk*8*512*4 B
    //  = molChunk*278,528 <= 2*perMolP*molChunk = molChunk*284,672.
    float* bufC = (float*)P0h;
    // Mol P1 (w1 split output, N=1024) aliases bufQ (qkv dead after attention):
    // 2 * molChunk*139*1024*2 B = molChunk*569,344 <= molChunk*854,016.
    unsigned short* P1h = (unsigned short*)bufQ;
    unsigned short* P1l = P1h + (size_t)molChunk * LSEQ * 1024;

    float* out_mol  = (float*)d_out;
    float* out_node = out_mol + (size_t)Bm * 512;
    float* out_ring = out_node + (size_t)N * 512;

    scan_kernel<<<1, 256, 0, stream>>>(rnn, R, mrn, Bm, rs, ms);

    // ---------------- mol weight conversion (RNE; once per launch) ----------------
    convert_w<<<(1536 * 512 / 4 + 255) / 256, 256, 0, stream>>>(m_wqkv, b_m_wqkv, 1536 * 512 / 4);
    convert_w<<<(512 * 512 / 4 + 255) / 256, 256, 0, stream>>>(m_wo, b_m_wo, 512 * 512 / 4);
    convert_w<<<(1024 * 512 / 4 + 255) / 256, 256, 0, stream>>>(m_w1, b_m_w1, 1024 * 512 / 4);
    convert_w<<<(512 * 1024 / 4 + 255) / 256, 256, 0, stream>>>(m_w2, b_m_w2, 512 * 1024 / 4);

    // ---------------- ring encoder (chunked, fp32 path — bit-identical results) ----------------
    for (int r0 = 0; r0 < R; r0 += ringChunk) {
        int RC = (R - r0 < ringChunk) ? (R - r0) : ringChunk;
        int TrC = RC * LRING;
        build_xr<<<(TrC * 128 + 255) / 256, 256, 0, stream>>>(x, rni, rnn, rs, bufA, r0, RC);
        gemm_nt<false, false><<<dim3(1536 / 128, (TrC + 127) / 128), 256, 0, stream>>>(
            bufA, r_wqkv, r_bqkv, nullptr, bufQ, TrC, 1536, 512);
        ring_attn<<<dim3(2, RC), 256, 0, stream>>>(bufQ, rnn, bufC, r0);
        gemm_nt<false, true><<<dim3(512 / 128, (TrC + 127) / 128), 256, 0, stream>>>(
            bufC, r_wo, r_bo, bufA, bufA, TrC, 512, 512);
        ln_kernel<<<TrC, 64, 0, stream>>>(bufA, r_ln1g, r_ln1b, nullptr, nullptr);
        gemm_nt<true, false><<<dim3(1024 / 128, (TrC + 127) / 128), 256, 0, stream>>>(
            bufA, r_w1, r_b1, nullptr, bufQ, TrC, 1024, 512);
        gemm_nt<false, true><<<dim3(512 / 128, (TrC + 127) / 128), 256, 0, stream>>>(
            bufQ, r_w2, r_b2, bufA, bufA, TrC, 512, 1024);
        ln_kernel<<<TrC, 64, 0, stream>>>(bufA, r_ln2g, r_ln2b, nullptr, nullptr);
        argmax_pick<<<(RC * 512 + 255) / 256, 256, 0, stream>>>(bufA, rings_vec + (size_t)r0 * 512, RC);
    }

    // ---------------- molecule encoder (chunked, MFMA split-A path) ----------------
    for (int c0 = 0; c0 < Bm; c0 += molChunk) {
        int CB = (Bm - c0 < molChunk) ? (Bm - c0) : molChunk;
        int TmC = CB * LSEQ;
        build_seq<<<(TmC * 128 + 255) / 256, 256, 0, stream>>>(
            x, rings_vec, CLS, RINGt, ENDt, ptr, mrn, ms, bufA, P0h, P0l, c0, CB);
        gemm_bf16<false, false, false><<<dim3(1536 / 128, (TmC + 127) / 128), 256, 0, stream>>>(
            P0h, P0l, b_m_wqkv, m_bqkv, nullptr, bufQ, nullptr, nullptr, TmC, 1536, 512);
        mol_attn<<<dim3(4, CB), 512, 0, stream>>>(bufQ, ptr, mrn, P0h, P0l, c0);
        gemm_bf16<false, true, false><<<dim3(512 / 128, (TmC + 127) / 128), 256, 0, stream>>>(
            P0h, P0l, b_m_wo, m_bo, bufA, bufA, nullptr, nullptr, TmC, 512, 512);
        ln_kernel<<<TmC, 64, 0, stream>>>(bufA, m_ln1g, m_ln1b, P0h, P0l);
        gemm_bf16<true, false, true><<<dim3(1024 / 128, (TmC + 127) / 128), 256, 0, stream>>>(
            P0h, P0l, b_m_w1, m_b1, nullptr, nullptr, P1h, P1l, TmC, 1024, 512);
        gemm_bf16<false, true, false><<<dim3(512 / 128, (TmC + 127) / 128), 256, 0, stream>>>(
            P1h, P1l, b_m_w2, m_b2, bufA, bufA, nullptr, nullptr, TmC, 512, 1024);
        ln_kernel<<<TmC, 64, 0, stream>>>(bufA, m_ln2g, m_ln2b, nullptr, nullptr);
        scatter_out<<<(TmC * 128 + 255) / 256, 256, 0, stream>>>(
            bufA, ptr, mrn, ms, out_mol, out_node, out_ring, c0, CB);
    }
}